// Round 1
// baseline (6912.346 us; speedup 1.0000x reference)
//
#include <hip/hip_runtime.h>

constexpr int NN = 50000;
constexpr int NE = 800000;
constexpr int XD = 92;
constexpr int ED = 80;
constexpr int HD = 128;
constexpr int C2 = 256;   // 2*HD
constexpr int IND = 336;  // 2*HD + ED
constexpr int NC = 3;
constexpr int NG = 256;

#define DINL __device__ __forceinline__

DINL float sigmoidf_(float x) { return 1.f / (1.f + __expf(-x)); }
DINL float softplusf_(float x) { return x > 20.f ? x : log1pf(__expf(x)); }

DINL void fma4(float4& a, float s, const float4& w) {
  a.x = fmaf(s, w.x, a.x);
  a.y = fmaf(s, w.y, a.y);
  a.z = fmaf(s, w.z, a.z);
  a.w = fmaf(s, w.w, a.w);
}

// ---------------- embed: h = x @ embW + embb ----------------
__global__ __launch_bounds__(256) void k_embed(const float* __restrict__ x,
    const float* __restrict__ W, const float* __restrict__ b, float* __restrict__ h) {
  __shared__ float xs[2][XD];
  int t = threadIdx.x;
  int n0 = blockIdx.x * 2;
  for (int i = t; i < 2 * XD; i += 256) xs[i / XD][i % XD] = x[(size_t)n0 * XD + i];
  __syncthreads();
  int lo = t >> 7, c = t & 127;
  float acc = b[c];
  for (int k = 0; k < XD; ++k) acc = fmaf(xs[lo][k], W[k * HD + c], acc);
  h[(size_t)(n0 + lo) * HD + c] = acc;
}

// ---------------- node projections: P1 = h@W1, P3 = h@W3 ----------------
__global__ __launch_bounds__(256) void k_nodeproj(const float* __restrict__ h,
    const float* __restrict__ W, float* __restrict__ P1, float* __restrict__ P3) {
  __shared__ float hs[8][HD];
  int t = threadIdx.x;
  int n0 = blockIdx.x * 8;
  for (int i = t; i < 8 * HD; i += 256) hs[i >> 7][i & 127] = h[(size_t)n0 * HD + i];
  __syncthreads();
  float a1[8], a3[8];
#pragma unroll
  for (int n = 0; n < 8; ++n) { a1[n] = 0.f; a3[n] = 0.f; }
  const float* W1 = W;             // rows 0..127
  const float* W3 = W + 208 * C2; // rows 208..335
  for (int k = 0; k < HD; ++k) {
    float w1 = W1[k * C2 + t], w3 = W3[k * C2 + t];
#pragma unroll
    for (int n = 0; n < 8; ++n) {
      a1[n] = fmaf(hs[n][k], w1, a1[n]);
      a3[n] = fmaf(hs[n][k], w3, a3[n]);
    }
  }
#pragma unroll
  for (int n = 0; n < 8; ++n) {
    P1[(size_t)(n0 + n) * C2 + t] = a1[n];
    P3[(size_t)(n0 + n) * C2 + t] = a3[n];
  }
}

// ---------------- edge pass 1: BN-input stats ----------------
// block = 256 threads = 4 waves; tile = 64 edges; wave owns 16 edges; lane owns 4 channels.
__global__ __launch_bounds__(256) void k_edgestat(
    const int* __restrict__ src, const int* __restrict__ dst,
    const float4* __restrict__ ea4, const float4* __restrict__ W24,
    const float4* __restrict__ b4, const float4* __restrict__ P14,
    const float4* __restrict__ P34, float* __restrict__ stats) {
  __shared__ float4 eas[64][20];
  __shared__ int ss[64], ds[64];
  __shared__ float red[4][512];
  int t = threadIdx.x;
  int w = t >> 6, l = t & 63;
  float4 bb = b4[l];
  float ssum[4] = {0.f, 0.f, 0.f, 0.f}, ssq[4] = {0.f, 0.f, 0.f, 0.f};
  const int ntiles = NE / 64;
  for (int tile = blockIdx.x; tile < ntiles; tile += gridDim.x) {
    int e0 = tile * 64;
    if (t < 64) ss[t] = src[e0 + t];
    else if (t < 128) ds[t - 64] = dst[e0 + t - 64];
    for (int i = t; i < 64 * 20; i += 256) eas[i / 20][i % 20] = ea4[(size_t)e0 * 20 + i];
    __syncthreads();
    float4 acc[16];
#pragma unroll
    for (int e = 0; e < 16; ++e) acc[e] = bb;
    for (int k4 = 0; k4 < 20; ++k4) {
      float4 w0 = W24[(k4 * 4 + 0) * 64 + l];
      float4 w1 = W24[(k4 * 4 + 1) * 64 + l];
      float4 w2 = W24[(k4 * 4 + 2) * 64 + l];
      float4 w3 = W24[(k4 * 4 + 3) * 64 + l];
#pragma unroll
      for (int e = 0; e < 16; ++e) {
        float4 av = eas[w * 16 + e][k4];
        fma4(acc[e], av.x, w0);
        fma4(acc[e], av.y, w1);
        fma4(acc[e], av.z, w2);
        fma4(acc[e], av.w, w3);
      }
    }
#pragma unroll
    for (int e = 0; e < 16; ++e) {
      int es = ss[w * 16 + e], ed = ds[w * 16 + e];
      float4 p1 = P14[(size_t)es * 64 + l];
      float4 p3 = P34[(size_t)ed * 64 + l];
      float m0 = acc[e].x + p1.x + p3.x;
      float m1 = acc[e].y + p1.y + p3.y;
      float m2 = acc[e].z + p1.z + p3.z;
      float m3 = acc[e].w + p1.w + p3.w;
      ssum[0] += m0; ssq[0] = fmaf(m0, m0, ssq[0]);
      ssum[1] += m1; ssq[1] = fmaf(m1, m1, ssq[1]);
      ssum[2] += m2; ssq[2] = fmaf(m2, m2, ssq[2]);
      ssum[3] += m3; ssq[3] = fmaf(m3, m3, ssq[3]);
    }
    __syncthreads();
  }
#pragma unroll
  for (int c = 0; c < 4; ++c) {
    red[w][4 * l + c] = ssum[c];
    red[w][256 + 4 * l + c] = ssq[c];
  }
  __syncthreads();
  for (int i = t; i < 512; i += 256)
    atomicAdd(&stats[i], red[0][i] + red[1][i] + red[2][i] + red[3][i]);
}

// ---------------- finalize BN: scale/shift from stats ----------------
__global__ void k_bnfin(const float* __restrict__ stats, float invcount,
                        const float* __restrict__ gamma, const float* __restrict__ beta,
                        int nch, float* __restrict__ out) {
  int t = blockIdx.x * blockDim.x + threadIdx.x;
  if (t < nch) {
    float mean = stats[t] * invcount;
    float var = stats[nch + t] * invcount - mean * mean;
    float istd = rsqrtf(var + 1e-5f);
    float sc = gamma[t] * istd;
    out[t] = sc;
    out[nch + t] = beta[t] - mean * sc;
  }
}

// ---------------- edge pass 2: BN + gate + scatter ----------------
__global__ __launch_bounds__(256) void k_edgeapply(
    const int* __restrict__ src, const int* __restrict__ dst,
    const float4* __restrict__ ea4, const float4* __restrict__ W24,
    const float4* __restrict__ b4, const float4* __restrict__ P14,
    const float4* __restrict__ P34, const float4* __restrict__ bns4,
    float* __restrict__ agg) {
  __shared__ float4 eas[64][20];
  __shared__ int ss[64], ds[64];
  int t = threadIdx.x;
  int w = t >> 6, l = t & 63;
  float4 bb = b4[l];
  float4 sc = bns4[l], sh = bns4[64 + l];
  const int ntiles = NE / 64;
  for (int tile = blockIdx.x; tile < ntiles; tile += gridDim.x) {
    int e0 = tile * 64;
    if (t < 64) ss[t] = src[e0 + t];
    else if (t < 128) ds[t - 64] = dst[e0 + t - 64];
    for (int i = t; i < 64 * 20; i += 256) eas[i / 20][i % 20] = ea4[(size_t)e0 * 20 + i];
    __syncthreads();
    float4 acc[16];
#pragma unroll
    for (int e = 0; e < 16; ++e) acc[e] = bb;
    for (int k4 = 0; k4 < 20; ++k4) {
      float4 w0 = W24[(k4 * 4 + 0) * 64 + l];
      float4 w1 = W24[(k4 * 4 + 1) * 64 + l];
      float4 w2 = W24[(k4 * 4 + 2) * 64 + l];
      float4 w3 = W24[(k4 * 4 + 3) * 64 + l];
#pragma unroll
      for (int e = 0; e < 16; ++e) {
        float4 av = eas[w * 16 + e][k4];
        fma4(acc[e], av.x, w0);
        fma4(acc[e], av.y, w1);
        fma4(acc[e], av.z, w2);
        fma4(acc[e], av.w, w3);
      }
    }
#pragma unroll
    for (int e = 0; e < 16; ++e) {
      int es = ss[w * 16 + e], ed = ds[w * 16 + e];
      float4 p1 = P14[(size_t)es * 64 + l];
      float4 p3 = P34[(size_t)ed * 64 + l];
      float4 v;
      v.x = fmaf(acc[e].x + p1.x + p3.x, sc.x, sh.x);
      v.y = fmaf(acc[e].y + p1.y + p3.y, sc.y, sh.y);
      v.z = fmaf(acc[e].z + p1.z + p3.z, sc.z, sh.z);
      v.w = fmaf(acc[e].w + p1.w + p3.w, sc.w, sh.w);
      // lane l<32 holds filt channels 4l..4l+3; lane l+32 holds core channels 4l+128..
      float ox = __shfl_xor(v.x, 32);
      float oy = __shfl_xor(v.y, 32);
      float oz = __shfl_xor(v.z, 32);
      float ow = __shfl_xor(v.w, 32);
      if (l < 32) {
        float* ap = agg + (size_t)es * HD + 4 * l;
        atomicAdd(ap + 0, sigmoidf_(v.x) * softplusf_(ox));
        atomicAdd(ap + 1, sigmoidf_(v.y) * softplusf_(oy));
        atomicAdd(ap + 2, sigmoidf_(v.z) * softplusf_(oz));
        atomicAdd(ap + 3, sigmoidf_(v.w) * softplusf_(ow));
      }
    }
    __syncthreads();
  }
}

// ---------------- agg BN stats (over nodes) ----------------
__global__ __launch_bounds__(256) void k_aggstat(const float* __restrict__ agg,
                                                 float* __restrict__ stats) {
  int t = threadIdx.x;
  int c = t & 127, half = t >> 7;
  float s = 0.f, sq = 0.f;
  for (int n = blockIdx.x * 2 + half; n < NN; n += gridDim.x * 2) {
    float v = agg[(size_t)n * HD + c];
    s += v;
    sq = fmaf(v, v, sq);
  }
  __shared__ float shs[2][128], shq[2][128];
  shs[half][c] = s;
  shq[half][c] = sq;
  __syncthreads();
  if (t < 128) {
    atomicAdd(&stats[c], shs[0][c] + shs[1][c]);
    atomicAdd(&stats[128 + c], shq[0][c] + shq[1][c]);
  }
}

// ---------------- h update: hn = softplus(h + bn(agg)) ----------------
__global__ __launch_bounds__(256) void k_update(const float* __restrict__ h,
    const float* __restrict__ agg, const float* __restrict__ bns, float* __restrict__ hn) {
  int stride = gridDim.x * 256;
  for (int i = blockIdx.x * 256 + threadIdx.x; i < NN * HD; i += stride) {
    int c = i & 127;
    float v = h[i] + fmaf(agg[i], bns[c], bns[128 + c]);
    hn[i] = softplusf_(v);
  }
}

// ---------------- pooling ----------------
__global__ __launch_bounds__(256) void k_pool(const float* __restrict__ h,
    const int* __restrict__ batch, float* __restrict__ psum, int* __restrict__ pcnt) {
  int stride = gridDim.x * 256;
  for (int i = blockIdx.x * 256 + threadIdx.x; i < NN * HD; i += stride) {
    int n = i >> 7, c = i & 127;
    int g = batch[n];
    atomicAdd(&psum[g * HD + c], h[i]);
    if (c == 0) atomicAdd(&pcnt[g], 1);
  }
}

// ---------------- head: softplus(pooled@linW+linb) @ outW + outb ----------------
__global__ __launch_bounds__(128) void k_head(const float* __restrict__ psum,
    const int* __restrict__ pcnt, const float* __restrict__ linW,
    const float* __restrict__ linb, const float* __restrict__ outW,
    const float* __restrict__ outb, float* __restrict__ out) {
  __shared__ float pl[HD];
  __shared__ float red[2];
  int g = blockIdx.x, t = threadIdx.x;
  float cnt = fmaxf((float)pcnt[g], 1.f);
  pl[t] = psum[g * HD + t] / cnt;
  __syncthreads();
  float acc = linb[t];
  for (int k = 0; k < HD; ++k) acc = fmaf(pl[k], linW[k * HD + t], acc);
  float term = softplusf_(acc) * outW[t];
#pragma unroll
  for (int off = 32; off > 0; off >>= 1) term += __shfl_down(term, off, 64);
  if ((t & 63) == 0) red[t >> 6] = term;
  __syncthreads();
  if (t == 0) out[g] = red[0] + red[1] + outb[0];
}

extern "C" void kernel_launch(void* const* d_in, const int* in_sizes, int n_in,
                              void* d_out, int out_size, void* d_ws, size_t ws_size,
                              hipStream_t stream) {
  const float* x = (const float*)d_in[0];
  const int* ei = (const int*)d_in[1];
  const float* ea = (const float*)d_in[2];
  const int* batch = (const int*)d_in[3];
  const float* embW = (const float*)d_in[4];
  const float* embb = (const float*)d_in[5];
  const float* convW = (const float*)d_in[6];
  const float* convb = (const float*)d_in[7];
  const float* big = (const float*)d_in[8];
  const float* bib = (const float*)d_in[9];
  const float* bog = (const float*)d_in[10];
  const float* bob = (const float*)d_in[11];
  const float* linW = (const float*)d_in[12];
  const float* linb = (const float*)d_in[13];
  const float* outW = (const float*)d_in[14];
  const float* outb = (const float*)d_in[15];
  float* out = (float*)d_out;

  float* wsf = (float*)d_ws;
  size_t off = 0;
  auto alloc = [&](size_t n) { float* p = wsf + off; off += n; return p; };
  float* h0 = alloc((size_t)NN * HD);
  float* h1 = alloc((size_t)NN * HD);
  float* P1 = alloc((size_t)NN * C2);
  float* P3 = alloc((size_t)NN * C2);
  float* agg = alloc((size_t)NN * HD);
  float* st_i = alloc(2 * C2);
  float* bnsi = alloc(2 * C2);
  float* st_o = alloc(2 * HD);
  float* bnso = alloc(2 * HD);
  float* psum = alloc((size_t)NG * HD);
  int* pcnt = (int*)alloc(NG);

  const int* srcp = ei;
  const int* dstp = ei + NE;

  k_embed<<<NN / 2, 256, 0, stream>>>(x, embW, embb, h0);

  float* hc = h0;
  float* hn = h1;
  for (int L = 0; L < NC; ++L) {
    const float* W = convW + (size_t)L * IND * C2;
    const float* W2 = W + (size_t)HD * C2;  // rows 128..207
    const float* bL = convb + (size_t)L * C2;
    hipMemsetAsync(st_i, 0, 2 * C2 * sizeof(float), stream);
    hipMemsetAsync(st_o, 0, 2 * HD * sizeof(float), stream);
    hipMemsetAsync(agg, 0, (size_t)NN * HD * sizeof(float), stream);

    k_nodeproj<<<NN / 8, 256, 0, stream>>>(hc, W, P1, P3);
    k_edgestat<<<2500, 256, 0, stream>>>(srcp, dstp, (const float4*)ea,
        (const float4*)W2, (const float4*)bL, (const float4*)P1, (const float4*)P3, st_i);
    k_bnfin<<<1, 256, 0, stream>>>(st_i, 1.f / NE, big + L * C2, bib + L * C2, C2, bnsi);
    k_edgeapply<<<NE / 64, 256, 0, stream>>>(srcp, dstp, (const float4*)ea,
        (const float4*)W2, (const float4*)bL, (const float4*)P1, (const float4*)P3,
        (const float4*)bnsi, agg);
    k_aggstat<<<512, 256, 0, stream>>>(agg, st_o);
    k_bnfin<<<1, 256, 0, stream>>>(st_o, 1.f / NN, bog + L * HD, bob + L * HD, HD, bnso);
    k_update<<<2048, 256, 0, stream>>>(hc, agg, bnso, hn);
    float* tmp = hc; hc = hn; hn = tmp;
  }

  hipMemsetAsync(psum, 0, (size_t)NG * HD * sizeof(float), stream);
  hipMemsetAsync(pcnt, 0, NG * sizeof(int), stream);
  k_pool<<<2048, 256, 0, stream>>>(hc, batch, psum, pcnt);
  k_head<<<NG, 128, 0, stream>>>(psum, pcnt, linW, linb, outW, outb, out);
}

// Round 2
// 6142.050 us; speedup vs baseline: 1.1254x; 1.1254x over previous
//
#include <hip/hip_runtime.h>

constexpr int NN = 50000;
constexpr int NE = 800000;
constexpr int XD = 92;
constexpr int ED = 80;
constexpr int HD = 128;
constexpr int C2 = 256;   // 2*HD
constexpr int IND = 336;  // 2*HD + ED
constexpr int NC = 3;
constexpr int NG = 256;

#define DINL __device__ __forceinline__

DINL float sigmoidf_(float x) { return 1.f / (1.f + __expf(-x)); }
DINL float softplusf_(float x) { return x > 20.f ? x : log1pf(__expf(x)); }

DINL void fma4(float4& a, float s, const float4& w) {
  a.x = fmaf(s, w.x, a.x);
  a.y = fmaf(s, w.y, a.y);
  a.z = fmaf(s, w.z, a.z);
  a.w = fmaf(s, w.w, a.w);
}

// ---------------- embed: h = x @ embW + embb ----------------
__global__ __launch_bounds__(256) void k_embed(const float* __restrict__ x,
    const float* __restrict__ W, const float* __restrict__ b, float* __restrict__ h) {
  __shared__ float xs[2][XD];
  int t = threadIdx.x;
  int n0 = blockIdx.x * 2;
  for (int i = t; i < 2 * XD; i += 256) xs[i / XD][i % XD] = x[(size_t)n0 * XD + i];
  __syncthreads();
  int lo = t >> 7, c = t & 127;
  float acc = b[c];
  for (int k = 0; k < XD; ++k) acc = fmaf(xs[lo][k], W[k * HD + c], acc);
  h[(size_t)(n0 + lo) * HD + c] = acc;
}

// ---------------- node projections: P1 = h@W1, P3 = h@W3 ----------------
__global__ __launch_bounds__(256) void k_nodeproj(const float* __restrict__ h,
    const float* __restrict__ W, float* __restrict__ P1, float* __restrict__ P3) {
  __shared__ float hs[8][HD];
  int t = threadIdx.x;
  int n0 = blockIdx.x * 8;
  for (int i = t; i < 8 * HD; i += 256) hs[i >> 7][i & 127] = h[(size_t)n0 * HD + i];
  __syncthreads();
  float a1[8], a3[8];
#pragma unroll
  for (int n = 0; n < 8; ++n) { a1[n] = 0.f; a3[n] = 0.f; }
  const float* W1 = W;             // rows 0..127
  const float* W3 = W + 208 * C2; // rows 208..335
  for (int k = 0; k < HD; ++k) {
    float w1 = W1[k * C2 + t], w3 = W3[k * C2 + t];
#pragma unroll
    for (int n = 0; n < 8; ++n) {
      a1[n] = fmaf(hs[n][k], w1, a1[n]);
      a3[n] = fmaf(hs[n][k], w3, a3[n]);
    }
  }
#pragma unroll
  for (int n = 0; n < 8; ++n) {
    P1[(size_t)(n0 + n) * C2 + t] = a1[n];
    P3[(size_t)(n0 + n) * C2 + t] = a3[n];
  }
}

// ---------------- CSR build: histogram / scan / scatter ----------------
__global__ __launch_bounds__(256) void k_hist(const int* __restrict__ src,
                                              int* __restrict__ deg) {
  for (int e = blockIdx.x * 256 + threadIdx.x; e < NE; e += gridDim.x * 256)
    atomicAdd(&deg[src[e]], 1);
}

__global__ __launch_bounds__(1024) void k_scan(const int* __restrict__ deg,
                                               int* __restrict__ cursor) {
  __shared__ int sums[1024];
  int t = threadIdx.x;
  const int CH = 49;  // ceil(50000/1024)
  int b0 = t * CH;
  int s = 0;
  for (int i = 0; i < CH; ++i) {
    int idx = b0 + i;
    if (idx < NN) s += deg[idx];
  }
  sums[t] = s;
  __syncthreads();
  for (int off = 1; off < 1024; off <<= 1) {
    int v = (t >= off) ? sums[t - off] : 0;
    __syncthreads();
    sums[t] += v;
    __syncthreads();
  }
  int excl = (t == 0) ? 0 : sums[t - 1];
  for (int i = 0; i < CH; ++i) {
    int idx = b0 + i;
    if (idx < NN) {
      cursor[idx] = excl;
      excl += deg[idx];
    }
  }
}

__global__ __launch_bounds__(256) void k_scatter(const int* __restrict__ src,
    const int* __restrict__ dst, int* __restrict__ cursor, int* __restrict__ eid,
    int* __restrict__ ssort, int* __restrict__ dsort) {
  for (int e = blockIdx.x * 256 + threadIdx.x; e < NE; e += gridDim.x * 256) {
    int s = src[e];
    int pos = atomicAdd(&cursor[s], 1);
    eid[pos] = e;
    ssort[pos] = s;
    dsort[pos] = dst[e];
  }
}

// ---------------- edge pass 1: BN-input stats (original edge order) ----------------
__global__ __launch_bounds__(256) void k_edgestat(
    const int* __restrict__ src, const int* __restrict__ dst,
    const float4* __restrict__ ea4, const float4* __restrict__ W24,
    const float4* __restrict__ b4, const float4* __restrict__ P14,
    const float4* __restrict__ P34, float* __restrict__ stats) {
  __shared__ float4 eas[64][20];
  __shared__ int ss[64], ds[64];
  __shared__ float red[4][512];
  int t = threadIdx.x;
  int w = t >> 6, l = t & 63;
  float4 bb = b4[l];
  float ssum[4] = {0.f, 0.f, 0.f, 0.f}, ssq[4] = {0.f, 0.f, 0.f, 0.f};
  const int ntiles = NE / 64;
  for (int tile = blockIdx.x; tile < ntiles; tile += gridDim.x) {
    int e0 = tile * 64;
    if (t < 64) ss[t] = src[e0 + t];
    else if (t < 128) ds[t - 64] = dst[e0 + t - 64];
    for (int i = t; i < 64 * 20; i += 256) eas[i / 20][i % 20] = ea4[(size_t)e0 * 20 + i];
    __syncthreads();
    float4 acc[16];
#pragma unroll
    for (int e = 0; e < 16; ++e) acc[e] = bb;
    for (int k4 = 0; k4 < 20; ++k4) {
      float4 w0 = W24[(k4 * 4 + 0) * 64 + l];
      float4 w1 = W24[(k4 * 4 + 1) * 64 + l];
      float4 w2 = W24[(k4 * 4 + 2) * 64 + l];
      float4 w3 = W24[(k4 * 4 + 3) * 64 + l];
#pragma unroll
      for (int e = 0; e < 16; ++e) {
        float4 av = eas[w * 16 + e][k4];
        fma4(acc[e], av.x, w0);
        fma4(acc[e], av.y, w1);
        fma4(acc[e], av.z, w2);
        fma4(acc[e], av.w, w3);
      }
    }
#pragma unroll
    for (int e = 0; e < 16; ++e) {
      int es = ss[w * 16 + e], ed = ds[w * 16 + e];
      float4 p1 = P14[(size_t)es * 64 + l];
      float4 p3 = P34[(size_t)ed * 64 + l];
      float m0 = acc[e].x + p1.x + p3.x;
      float m1 = acc[e].y + p1.y + p3.y;
      float m2 = acc[e].z + p1.z + p3.z;
      float m3 = acc[e].w + p1.w + p3.w;
      ssum[0] += m0; ssq[0] = fmaf(m0, m0, ssq[0]);
      ssum[1] += m1; ssq[1] = fmaf(m1, m1, ssq[1]);
      ssum[2] += m2; ssq[2] = fmaf(m2, m2, ssq[2]);
      ssum[3] += m3; ssq[3] = fmaf(m3, m3, ssq[3]);
    }
    __syncthreads();
  }
#pragma unroll
  for (int c = 0; c < 4; ++c) {
    red[w][4 * l + c] = ssum[c];
    red[w][256 + 4 * l + c] = ssq[c];
  }
  __syncthreads();
  for (int i = t; i < 512; i += 256)
    atomicAdd(&stats[i], red[0][i] + red[1][i] + red[2][i] + red[3][i]);
}

// ---------------- finalize BN ----------------
__global__ void k_bnfin(const float* __restrict__ stats, float invcount,
                        const float* __restrict__ gamma, const float* __restrict__ beta,
                        int nch, float* __restrict__ out) {
  int t = blockIdx.x * blockDim.x + threadIdx.x;
  if (t < nch) {
    float mean = stats[t] * invcount;
    float var = stats[nch + t] * invcount - mean * mean;
    float istd = rsqrtf(var + 1e-5f);
    float sc = gamma[t] * istd;
    out[t] = sc;
    out[nch + t] = beta[t] - mean * sc;
  }
}

// ---------------- edge pass 2 (CSR order): BN + gate + segmented scatter ----------------
// tile = 64 CSR slots; wave owns 16 consecutive slots -> same-src runs reduce in-register,
// atomics only at run boundaries.
__global__ __launch_bounds__(256) void k_edgeapply(
    const int* __restrict__ eid, const int* __restrict__ ssort,
    const int* __restrict__ dsort, const float4* __restrict__ ea4,
    const float4* __restrict__ W24, const float4* __restrict__ b4,
    const float4* __restrict__ P14, const float4* __restrict__ P34,
    const float4* __restrict__ bns4, float* __restrict__ agg) {
  __shared__ float4 eas[64][20];
  __shared__ int es_[64], ss[64], ds[64];
  int t = threadIdx.x;
  int w = t >> 6, l = t & 63;
  float4 bb = b4[l];
  float4 sc = bns4[l], sh = bns4[64 + l];
  int e0 = blockIdx.x * 64;
  if (t < 64) {
    es_[t] = eid[e0 + t];
    ss[t] = ssort[e0 + t];
    ds[t] = dsort[e0 + t];
  }
  __syncthreads();
  for (int i = t; i < 64 * 20; i += 256) {
    int e = i / 20, k = i % 20;
    eas[e][k] = ea4[(size_t)es_[e] * 20 + k];
  }
  __syncthreads();
  float4 acc[16];
#pragma unroll
  for (int e = 0; e < 16; ++e) acc[e] = bb;
  for (int k4 = 0; k4 < 20; ++k4) {
    float4 w0 = W24[(k4 * 4 + 0) * 64 + l];
    float4 w1 = W24[(k4 * 4 + 1) * 64 + l];
    float4 w2 = W24[(k4 * 4 + 2) * 64 + l];
    float4 w3 = W24[(k4 * 4 + 3) * 64 + l];
#pragma unroll
    for (int e = 0; e < 16; ++e) {
      float4 av = eas[w * 16 + e][k4];
      fma4(acc[e], av.x, w0);
      fma4(acc[e], av.y, w1);
      fma4(acc[e], av.z, w2);
      fma4(acc[e], av.w, w3);
    }
  }
  // gated channel owned by this lane: l<32 -> ch 4l,4l+1 ; l>=32 -> ch 4(l-32)+2, 4(l-32)+3
  int ch = (l < 32) ? 4 * l : 4 * (l - 32) + 2;
  int base = w * 16;
  float r0 = 0.f, r1 = 0.f;
  int curs = ss[base];
#pragma unroll
  for (int e = 0; e < 16; ++e) {
    int es = ss[base + e], ed = ds[base + e];
    float4 p1 = P14[(size_t)es * 64 + l];
    float4 p3 = P34[(size_t)ed * 64 + l];
    float4 v;
    v.x = fmaf(acc[e].x + p1.x + p3.x, sc.x, sh.x);
    v.y = fmaf(acc[e].y + p1.y + p3.y, sc.y, sh.y);
    v.z = fmaf(acc[e].z + p1.z + p3.z, sc.z, sh.z);
    v.w = fmaf(acc[e].w + p1.w + p3.w, sc.w, sh.w);
    float ox = __shfl_xor(v.x, 32);
    float oy = __shfl_xor(v.y, 32);
    float oz = __shfl_xor(v.z, 32);
    float ow = __shfl_xor(v.w, 32);
    float g0, g1;
    if (l < 32) {  // filt native (v), core received (o)
      g0 = sigmoidf_(v.x) * softplusf_(ox);
      g1 = sigmoidf_(v.y) * softplusf_(oy);
    } else {  // core native (v), filt received (o)
      g0 = sigmoidf_(oz) * softplusf_(v.z);
      g1 = sigmoidf_(ow) * softplusf_(v.w);
    }
    if (es != curs) {  // wave-uniform branch: flush previous src run
      atomicAdd(&agg[(size_t)curs * HD + ch], r0);
      atomicAdd(&agg[(size_t)curs * HD + ch + 1], r1);
      r0 = 0.f;
      r1 = 0.f;
      curs = es;
    }
    r0 += g0;
    r1 += g1;
  }
  atomicAdd(&agg[(size_t)curs * HD + ch], r0);
  atomicAdd(&agg[(size_t)curs * HD + ch + 1], r1);
}

// ---------------- agg BN stats (over nodes) ----------------
__global__ __launch_bounds__(256) void k_aggstat(const float* __restrict__ agg,
                                                 float* __restrict__ stats) {
  int t = threadIdx.x;
  int c = t & 127, half = t >> 7;
  float s = 0.f, sq = 0.f;
  for (int n = blockIdx.x * 2 + half; n < NN; n += gridDim.x * 2) {
    float v = agg[(size_t)n * HD + c];
    s += v;
    sq = fmaf(v, v, sq);
  }
  __shared__ float shs[2][128], shq[2][128];
  shs[half][c] = s;
  shq[half][c] = sq;
  __syncthreads();
  if (t < 128) {
    atomicAdd(&stats[c], shs[0][c] + shs[1][c]);
    atomicAdd(&stats[128 + c], shq[0][c] + shq[1][c]);
  }
}

// ---------------- h update ----------------
__global__ __launch_bounds__(256) void k_update(const float* __restrict__ h,
    const float* __restrict__ agg, const float* __restrict__ bns, float* __restrict__ hn) {
  int stride = gridDim.x * 256;
  for (int i = blockIdx.x * 256 + threadIdx.x; i < NN * HD; i += stride) {
    int c = i & 127;
    float v = h[i] + fmaf(agg[i], bns[c], bns[128 + c]);
    hn[i] = softplusf_(v);
  }
}

// ---------------- pooling ----------------
__global__ __launch_bounds__(256) void k_pool(const float* __restrict__ h,
    const int* __restrict__ batch, float* __restrict__ psum, int* __restrict__ pcnt) {
  int stride = gridDim.x * 256;
  for (int i = blockIdx.x * 256 + threadIdx.x; i < NN * HD; i += stride) {
    int n = i >> 7, c = i & 127;
    int g = batch[n];
    atomicAdd(&psum[g * HD + c], h[i]);
    if (c == 0) atomicAdd(&pcnt[g], 1);
  }
}

// ---------------- head ----------------
__global__ __launch_bounds__(128) void k_head(const float* __restrict__ psum,
    const int* __restrict__ pcnt, const float* __restrict__ linW,
    const float* __restrict__ linb, const float* __restrict__ outW,
    const float* __restrict__ outb, float* __restrict__ out) {
  __shared__ float pl[HD];
  __shared__ float red[2];
  int g = blockIdx.x, t = threadIdx.x;
  float cnt = fmaxf((float)pcnt[g], 1.f);
  pl[t] = psum[g * HD + t] / cnt;
  __syncthreads();
  float acc = linb[t];
  for (int k = 0; k < HD; ++k) acc = fmaf(pl[k], linW[k * HD + t], acc);
  float term = softplusf_(acc) * outW[t];
#pragma unroll
  for (int off = 32; off > 0; off >>= 1) term += __shfl_down(term, off, 64);
  if ((t & 63) == 0) red[t >> 6] = term;
  __syncthreads();
  if (t == 0) out[g] = red[0] + red[1] + outb[0];
}

extern "C" void kernel_launch(void* const* d_in, const int* in_sizes, int n_in,
                              void* d_out, int out_size, void* d_ws, size_t ws_size,
                              hipStream_t stream) {
  const float* x = (const float*)d_in[0];
  const int* ei = (const int*)d_in[1];
  const float* ea = (const float*)d_in[2];
  const int* batch = (const int*)d_in[3];
  const float* embW = (const float*)d_in[4];
  const float* embb = (const float*)d_in[5];
  const float* convW = (const float*)d_in[6];
  const float* convb = (const float*)d_in[7];
  const float* big = (const float*)d_in[8];
  const float* bib = (const float*)d_in[9];
  const float* bog = (const float*)d_in[10];
  const float* bob = (const float*)d_in[11];
  const float* linW = (const float*)d_in[12];
  const float* linb = (const float*)d_in[13];
  const float* outW = (const float*)d_in[14];
  const float* outb = (const float*)d_in[15];
  float* out = (float*)d_out;

  float* wsf = (float*)d_ws;
  size_t off = 0;
  auto alloc = [&](size_t n) { float* p = wsf + off; off += n; return p; };
  float* h0 = alloc((size_t)NN * HD);
  float* h1 = alloc((size_t)NN * HD);
  float* P1 = alloc((size_t)NN * C2);
  float* P3 = alloc((size_t)NN * C2);
  float* agg = alloc((size_t)NN * HD);
  float* st_i = alloc(2 * C2);
  float* bnsi = alloc(2 * C2);
  float* st_o = alloc(2 * HD);
  float* bnso = alloc(2 * HD);
  float* psum = alloc((size_t)NG * HD);
  int* pcnt = (int*)alloc(NG);
  int* deg = (int*)alloc(NN);
  int* cursor = (int*)alloc(NN);
  int* eid = (int*)alloc(NE);
  int* ssort = (int*)alloc(NE);
  int* dsort = (int*)alloc(NE);

  const int* srcp = ei;
  const int* dstp = ei + NE;

  // CSR build (per call; edge_index is constant but no cross-call state allowed)
  hipMemsetAsync(deg, 0, NN * sizeof(int), stream);
  k_hist<<<2048, 256, 0, stream>>>(srcp, deg);
  k_scan<<<1, 1024, 0, stream>>>(deg, cursor);
  k_scatter<<<2048, 256, 0, stream>>>(srcp, dstp, cursor, eid, ssort, dsort);

  k_embed<<<NN / 2, 256, 0, stream>>>(x, embW, embb, h0);

  float* hc = h0;
  float* hn = h1;
  for (int L = 0; L < NC; ++L) {
    const float* W = convW + (size_t)L * IND * C2;
    const float* W2 = W + (size_t)HD * C2;  // rows 128..207
    const float* bL = convb + (size_t)L * C2;
    hipMemsetAsync(st_i, 0, 2 * C2 * sizeof(float), stream);
    hipMemsetAsync(st_o, 0, 2 * HD * sizeof(float), stream);
    hipMemsetAsync(agg, 0, (size_t)NN * HD * sizeof(float), stream);

    k_nodeproj<<<NN / 8, 256, 0, stream>>>(hc, W, P1, P3);
    k_edgestat<<<2500, 256, 0, stream>>>(srcp, dstp, (const float4*)ea,
        (const float4*)W2, (const float4*)bL, (const float4*)P1, (const float4*)P3, st_i);
    k_bnfin<<<1, 256, 0, stream>>>(st_i, 1.f / NE, big + L * C2, bib + L * C2, C2, bnsi);
    k_edgeapply<<<NE / 64, 256, 0, stream>>>(eid, ssort, dsort, (const float4*)ea,
        (const float4*)W2, (const float4*)bL, (const float4*)P1, (const float4*)P3,
        (const float4*)bnsi, agg);
    k_aggstat<<<512, 256, 0, stream>>>(agg, st_o);
    k_bnfin<<<1, 256, 0, stream>>>(st_o, 1.f / NN, bog + L * HD, bob + L * HD, HD, bnso);
    k_update<<<2048, 256, 0, stream>>>(hc, agg, bnso, hn);
    float* tmp = hc; hc = hn; hn = tmp;
  }

  hipMemsetAsync(psum, 0, (size_t)NG * HD * sizeof(float), stream);
  hipMemsetAsync(pcnt, 0, NG * sizeof(int), stream);
  k_pool<<<2048, 256, 0, stream>>>(hc, batch, psum, pcnt);
  k_head<<<NG, 128, 0, stream>>>(psum, pcnt, linW, linb, outW, outb, out);
}

// Round 3
// 4691.121 us; speedup vs baseline: 1.4735x; 1.3093x over previous
//
#include <hip/hip_runtime.h>

constexpr int NN = 50000;
constexpr int NE = 800000;
constexpr int XD = 92;
constexpr int ED = 80;
constexpr int HD = 128;
constexpr int C2 = 256;   // 2*HD
constexpr int IND = 336;  // 2*HD + ED
constexpr int NC = 3;
constexpr int NG = 256;
constexpr int NTILES = NE / 64;      // 12500
constexpr int WSZ_L = 16 * 3 * 64 * 8;  // per-layer swizzled W2: 24576 ushort

#define DINL __device__ __forceinline__

typedef __attribute__((ext_vector_type(8))) short bf16x8;
typedef __attribute__((ext_vector_type(4))) float f32x4;

DINL float sigmoidf_(float x) { return 1.f / (1.f + __expf(-x)); }
DINL float softplusf_(float x) { return x > 20.f ? x : log1pf(__expf(x)); }
DINL short f2bf(float f) {
  unsigned u = __float_as_uint(f);
  u = (u + 0x7fffu + ((u >> 16) & 1u)) >> 16;
  return (short)u;
}

// ---------------- embed ----------------
__global__ __launch_bounds__(256) void k_embed(const float* __restrict__ x,
    const float* __restrict__ W, const float* __restrict__ b, float* __restrict__ h) {
  __shared__ float xs[2][XD];
  int t = threadIdx.x;
  int n0 = blockIdx.x * 2;
  for (int i = t; i < 2 * XD; i += 256) xs[i / XD][i % XD] = x[(size_t)n0 * XD + i];
  __syncthreads();
  int lo = t >> 7, c = t & 127;
  float acc = b[c];
  for (int k = 0; k < XD; ++k) acc = fmaf(xs[lo][k], W[k * HD + c], acc);
  h[(size_t)(n0 + lo) * HD + c] = acc;
}

// ---------------- node projections ----------------
__global__ __launch_bounds__(256) void k_nodeproj(const float* __restrict__ h,
    const float* __restrict__ W, float* __restrict__ P1, float* __restrict__ P3) {
  __shared__ float hs[8][HD];
  int t = threadIdx.x;
  int n0 = blockIdx.x * 8;
  for (int i = t; i < 8 * HD; i += 256) hs[i >> 7][i & 127] = h[(size_t)n0 * HD + i];
  __syncthreads();
  float a1[8], a3[8];
#pragma unroll
  for (int n = 0; n < 8; ++n) { a1[n] = 0.f; a3[n] = 0.f; }
  const float* W1 = W;
  const float* W3 = W + 208 * C2;
  for (int k = 0; k < HD; ++k) {
    float w1 = W1[k * C2 + t], w3 = W3[k * C2 + t];
#pragma unroll
    for (int n = 0; n < 8; ++n) {
      a1[n] = fmaf(hs[n][k], w1, a1[n]);
      a3[n] = fmaf(hs[n][k], w3, a3[n]);
    }
  }
#pragma unroll
  for (int n = 0; n < 8; ++n) {
    P1[(size_t)(n0 + n) * C2 + t] = a1[n];
    P3[(size_t)(n0 + n) * C2 + t] = a3[n];
  }
}

// ---------------- CSR build ----------------
__global__ __launch_bounds__(256) void k_hist(const int* __restrict__ src,
                                              int* __restrict__ deg) {
  for (int e = blockIdx.x * 256 + threadIdx.x; e < NE; e += gridDim.x * 256)
    atomicAdd(&deg[src[e]], 1);
}

__global__ __launch_bounds__(1024) void k_scan(const int* __restrict__ deg,
                                               int* __restrict__ cursor) {
  __shared__ int sums[1024];
  int t = threadIdx.x;
  const int CH = 49;
  int b0 = t * CH;
  int s = 0;
  for (int i = 0; i < CH; ++i) {
    int idx = b0 + i;
    if (idx < NN) s += deg[idx];
  }
  sums[t] = s;
  __syncthreads();
  for (int off = 1; off < 1024; off <<= 1) {
    int v = (t >= off) ? sums[t - off] : 0;
    __syncthreads();
    sums[t] += v;
    __syncthreads();
  }
  int excl = (t == 0) ? 0 : sums[t - 1];
  for (int i = 0; i < CH; ++i) {
    int idx = b0 + i;
    if (idx < NN) {
      cursor[idx] = excl;
      excl += deg[idx];
    }
  }
}

__global__ __launch_bounds__(256) void k_scatter(const int* __restrict__ src,
    const int* __restrict__ dst, int* __restrict__ cursor, int* __restrict__ eid,
    int* __restrict__ ssort, int* __restrict__ dsort) {
  for (int e = blockIdx.x * 256 + threadIdx.x; e < NE; e += gridDim.x * 256) {
    int s = src[e];
    int pos = atomicAdd(&cursor[s], 1);
    eid[pos] = e;
    ssort[pos] = s;
    dsort[pos] = dst[e];
  }
}

// ---------------- W2 -> MFMA fragment pre-swizzle ----------------
// layout per layer: [(mt*3+ks)*64 + lane]*8 + j ; A[m][k] = W2[k][m]
// lane = 16g+r : holds A[mt*16+r][ks*32+8g+j]
__global__ __launch_bounds__(256) void k_wprep(const float* __restrict__ convW,
                                               unsigned short* __restrict__ Wswz) {
  int idx = blockIdx.x * 256 + threadIdx.x;
  if (idx >= NC * WSZ_L) return;
  int L = idx / WSZ_L;
  int rem = idx - L * WSZ_L;
  int mt = rem / 1536;
  int rem2 = rem - mt * 1536;
  int ks = rem2 >> 9;
  int lane = (rem2 >> 3) & 63;
  int j = rem2 & 7;
  int k = ks * 32 + (lane >> 4) * 8 + j;
  int m = mt * 16 + (lane & 15);
  float v = (k < ED) ? convW[(size_t)L * IND * C2 + (size_t)(HD + k) * C2 + m] : 0.f;
  Wswz[idx] = (unsigned short)f2bf(v);
}

// ---------------- shared MFMA tile machinery ----------------
// block = 256 = 4 waves. tile = 64 edges (CSR order). D[ch][edge].
// wave w owns m-tiles {2w,2w+1,2w+8,2w+9}; lane 16g+c -> channels mtg*16+4g..+3, edge col c.

DINL void stage_tile(int t, int e0, const int* eid, const int* ssort, const int* dsort,
                     const float* __restrict__ ea, int* ei_, int* se, int* de,
                     bf16x8* Bls) {
  if (t < 64) ei_[t] = eid[e0 + t];
  else if (t < 128) se[t - 64] = ssort[e0 + t - 64];
  else if (t < 192) de[t - 128] = dsort[e0 + t - 128];
  __syncthreads();
  for (int i = t; i < 768; i += 256) {
    int fl = i & 63;
    int fr = i >> 6;          // nt*3+ks
    int nt = fr / 3, ks = fr - 3 * nt;
    int rr = fl & 15, gg = fl >> 4;
    int k0 = ks * 32 + gg * 8;
    bf16x8 v;
    if (k0 < ED) {
      const float* p = ea + (size_t)ei_[nt * 16 + rr] * ED + k0;
      float4 x0 = *(const float4*)p;
      float4 x1 = *(const float4*)(p + 4);
      v[0] = f2bf(x0.x); v[1] = f2bf(x0.y); v[2] = f2bf(x0.z); v[3] = f2bf(x0.w);
      v[4] = f2bf(x1.x); v[5] = f2bf(x1.y); v[6] = f2bf(x1.z); v[7] = f2bf(x1.w);
    } else {
#pragma unroll
      for (int j = 0; j < 8; ++j) v[j] = 0;
    }
    Bls[fr * 64 + fl] = v;
  }
  __syncthreads();
}

// ---------------- edge pass 1: BN-input stats (MFMA) ----------------
__global__ __launch_bounds__(256) void k_estat(
    const int* __restrict__ eid, const int* __restrict__ ssort, const int* __restrict__ dsort,
    const float* __restrict__ ea, const unsigned short* __restrict__ Wswz,
    const float* __restrict__ bias, const float4* __restrict__ P14,
    const float4* __restrict__ P34, float* __restrict__ stats) {
  __shared__ bf16x8 Bls[768];
  __shared__ int ei_[64], se[64], de[64];
  int t = threadIdx.x;
  int w = t >> 6, l = t & 63;
  int g = l >> 4, c = l & 15;
  int mtg[4] = {2 * w, 2 * w + 1, 2 * w + 8, 2 * w + 9};
  const bf16x8* Wf = (const bf16x8*)Wswz;
  bf16x8 af[4][3];
  f32x4 bias4[4];
#pragma unroll
  for (int m = 0; m < 4; ++m) {
#pragma unroll
    for (int ks = 0; ks < 3; ++ks) af[m][ks] = Wf[(mtg[m] * 3 + ks) * 64 + l];
    float4 bb = ((const float4*)bias)[mtg[m] * 4 + g];
    bias4[m][0] = bb.x; bias4[m][1] = bb.y; bias4[m][2] = bb.z; bias4[m][3] = bb.w;
  }
  f32x4 ssum[4], ssq[4];
#pragma unroll
  for (int m = 0; m < 4; ++m)
#pragma unroll
    for (int i = 0; i < 4; ++i) { ssum[m][i] = 0.f; ssq[m][i] = 0.f; }

  for (int tile = blockIdx.x; tile < NTILES; tile += gridDim.x) {
    stage_tile(t, tile * 64, eid, ssort, dsort, ea, ei_, se, de, Bls);
    f32x4 acc[4][4];
#pragma unroll
    for (int m = 0; m < 4; ++m)
#pragma unroll
      for (int n = 0; n < 4; ++n)
#pragma unroll
        for (int i = 0; i < 4; ++i) acc[m][n][i] = 0.f;
#pragma unroll
    for (int nt = 0; nt < 4; ++nt)
#pragma unroll
      for (int ks = 0; ks < 3; ++ks) {
        bf16x8 bfrag = Bls[(nt * 3 + ks) * 64 + l];
#pragma unroll
        for (int m = 0; m < 4; ++m)
          acc[m][nt] = __builtin_amdgcn_mfma_f32_16x16x32_bf16(af[m][ks], bfrag,
                                                               acc[m][nt], 0, 0, 0);
      }
#pragma unroll
    for (int nt = 0; nt < 4; ++nt) {
      int s_ = se[nt * 16 + c], d_ = de[nt * 16 + c];
#pragma unroll
      for (int m = 0; m < 4; ++m) {
        float4 p1 = P14[(size_t)s_ * 64 + mtg[m] * 4 + g];
        float4 p3 = P34[(size_t)d_ * 64 + mtg[m] * 4 + g];
        f32x4 ms;
        ms[0] = acc[m][nt][0] + bias4[m][0] + p1.x + p3.x;
        ms[1] = acc[m][nt][1] + bias4[m][1] + p1.y + p3.y;
        ms[2] = acc[m][nt][2] + bias4[m][2] + p1.z + p3.z;
        ms[3] = acc[m][nt][3] + bias4[m][3] + p1.w + p3.w;
#pragma unroll
        for (int i = 0; i < 4; ++i) {
          ssum[m][i] += ms[i];
          ssq[m][i] = fmaf(ms[i], ms[i], ssq[m][i]);
        }
      }
    }
    __syncthreads();
  }
#pragma unroll
  for (int off = 1; off < 16; off <<= 1)
#pragma unroll
    for (int m = 0; m < 4; ++m)
#pragma unroll
      for (int i = 0; i < 4; ++i) {
        ssum[m][i] += __shfl_xor(ssum[m][i], off, 16);
        ssq[m][i] += __shfl_xor(ssq[m][i], off, 16);
      }
  if (c == 0) {
#pragma unroll
    for (int m = 0; m < 4; ++m)
#pragma unroll
      for (int i = 0; i < 4; ++i) {
        int ch = mtg[m] * 16 + 4 * g + i;
        atomicAdd(&stats[ch], ssum[m][i]);
        atomicAdd(&stats[C2 + ch], ssq[m][i]);
      }
  }
}

// ---------------- finalize BN ----------------
__global__ void k_bnfin(const float* __restrict__ stats, float invcount,
                        const float* __restrict__ gamma, const float* __restrict__ beta,
                        int nch, float* __restrict__ out) {
  int t = blockIdx.x * blockDim.x + threadIdx.x;
  if (t < nch) {
    float mean = stats[t] * invcount;
    float var = stats[nch + t] * invcount - mean * mean;
    float istd = rsqrtf(var + 1e-5f);
    float sc = gamma[t] * istd;
    out[t] = sc;
    out[nch + t] = beta[t] - mean * sc;
  }
}

// ---------------- edge pass 2: MFMA + BN + gate + segmented scatter ----------------
__global__ __launch_bounds__(256) void k_eapply(
    const int* __restrict__ eid, const int* __restrict__ ssort, const int* __restrict__ dsort,
    const float* __restrict__ ea, const unsigned short* __restrict__ Wswz,
    const float* __restrict__ bias, const float4* __restrict__ P14,
    const float4* __restrict__ P34, const float* __restrict__ bns,
    float* __restrict__ agg) {
  __shared__ bf16x8 Bls[768];
  __shared__ int ei_[64], se[64], de[64];
  int t = threadIdx.x;
  int w = t >> 6, l = t & 63;
  int g = l >> 4, c = l & 15;
  int mtg[4] = {2 * w, 2 * w + 1, 2 * w + 8, 2 * w + 9};
  const bf16x8* Wf = (const bf16x8*)Wswz;
  bf16x8 af[4][3];
  f32x4 bias4[4], sc4[4], sh4[4];
#pragma unroll
  for (int m = 0; m < 4; ++m) {
#pragma unroll
    for (int ks = 0; ks < 3; ++ks) af[m][ks] = Wf[(mtg[m] * 3 + ks) * 64 + l];
    float4 bb = ((const float4*)bias)[mtg[m] * 4 + g];
    float4 s1 = ((const float4*)bns)[mtg[m] * 4 + g];
    float4 s2 = ((const float4*)bns)[64 + mtg[m] * 4 + g];
    bias4[m][0] = bb.x; bias4[m][1] = bb.y; bias4[m][2] = bb.z; bias4[m][3] = bb.w;
    sc4[m][0] = s1.x; sc4[m][1] = s1.y; sc4[m][2] = s1.z; sc4[m][3] = s1.w;
    sh4[m][0] = s2.x; sh4[m][1] = s2.y; sh4[m][2] = s2.z; sh4[m][3] = s2.w;
  }

  for (int tile = blockIdx.x; tile < NTILES; tile += gridDim.x) {
    stage_tile(t, tile * 64, eid, ssort, dsort, ea, ei_, se, de, Bls);
    f32x4 acc[4][4];
#pragma unroll
    for (int m = 0; m < 4; ++m)
#pragma unroll
      for (int n = 0; n < 4; ++n)
#pragma unroll
        for (int i = 0; i < 4; ++i) acc[m][n][i] = 0.f;
#pragma unroll
    for (int nt = 0; nt < 4; ++nt)
#pragma unroll
      for (int ks = 0; ks < 3; ++ks) {
        bf16x8 bfrag = Bls[(nt * 3 + ks) * 64 + l];
#pragma unroll
        for (int m = 0; m < 4; ++m)
          acc[m][nt] = __builtin_amdgcn_mfma_f32_16x16x32_bf16(af[m][ks], bfrag,
                                                               acc[m][nt], 0, 0, 0);
      }
#pragma unroll
    for (int nt = 0; nt < 4; ++nt) {
      int s_ = se[nt * 16 + c], d_ = de[nt * 16 + c];
      // segment structure across the 16 edge-lanes (CSR-sorted => runs)
      int ps = __shfl_up(s_, 1, 16);
      bool head = (c == 0) || (ps != s_);
      int hp = head ? c : 0;
#pragma unroll
      for (int dd = 1; dd < 16; dd <<= 1) {
        int t2 = __shfl_up(hp, dd, 16);
        if (c >= dd) hp = max(hp, t2);
      }
      int ns = __shfl_down(s_, 1, 16);
      bool tail = (c == 15) || (ns != s_);

      f32x4 v4[4];
#pragma unroll
      for (int m = 0; m < 4; ++m) {
        float4 p1 = P14[(size_t)s_ * 64 + mtg[m] * 4 + g];
        float4 p3 = P34[(size_t)d_ * 64 + mtg[m] * 4 + g];
        v4[m][0] = fmaf(acc[m][nt][0] + bias4[m][0] + p1.x + p3.x, sc4[m][0], sh4[m][0]);
        v4[m][1] = fmaf(acc[m][nt][1] + bias4[m][1] + p1.y + p3.y, sc4[m][1], sh4[m][1]);
        v4[m][2] = fmaf(acc[m][nt][2] + bias4[m][2] + p1.z + p3.z, sc4[m][2], sh4[m][2]);
        v4[m][3] = fmaf(acc[m][nt][3] + bias4[m][3] + p1.w + p3.w, sc4[m][3], sh4[m][3]);
      }
      float gg[8];
#pragma unroll
      for (int p = 0; p < 2; ++p)
#pragma unroll
        for (int i = 0; i < 4; ++i)
          gg[p * 4 + i] = sigmoidf_(v4[p][i]) * softplusf_(v4[p + 2][i]);
      // segmented inclusive sum over lanes [hp..c]
#pragma unroll
      for (int dd = 1; dd < 16; dd <<= 1) {
#pragma unroll
        for (int q = 0; q < 8; ++q) {
          float tv = __shfl_up(gg[q], dd, 16);
          if (c - dd >= hp) gg[q] += tv;
        }
      }
      if (tail) {
#pragma unroll
        for (int p = 0; p < 2; ++p)
#pragma unroll
          for (int i = 0; i < 4; ++i)
            atomicAdd(&agg[(size_t)s_ * HD + mtg[p] * 16 + 4 * g + i], gg[p * 4 + i]);
      }
    }
    __syncthreads();
  }
}

// ---------------- agg BN stats ----------------
__global__ __launch_bounds__(256) void k_aggstat(const float* __restrict__ agg,
                                                 float* __restrict__ stats) {
  int t = threadIdx.x;
  int c = t & 127, half = t >> 7;
  float s = 0.f, sq = 0.f;
  for (int n = blockIdx.x * 2 + half; n < NN; n += gridDim.x * 2) {
    float v = agg[(size_t)n * HD + c];
    s += v;
    sq = fmaf(v, v, sq);
  }
  __shared__ float shs[2][128], shq[2][128];
  shs[half][c] = s;
  shq[half][c] = sq;
  __syncthreads();
  if (t < 128) {
    atomicAdd(&stats[c], shs[0][c] + shs[1][c]);
    atomicAdd(&stats[128 + c], shq[0][c] + shq[1][c]);
  }
}

// ---------------- h update ----------------
__global__ __launch_bounds__(256) void k_update(const float* __restrict__ h,
    const float* __restrict__ agg, const float* __restrict__ bns, float* __restrict__ hn) {
  int stride = gridDim.x * 256;
  for (int i = blockIdx.x * 256 + threadIdx.x; i < NN * HD; i += stride) {
    int c = i & 127;
    float v = h[i] + fmaf(agg[i], bns[c], bns[128 + c]);
    hn[i] = softplusf_(v);
  }
}

// ---------------- pooling ----------------
__global__ __launch_bounds__(256) void k_pool(const float* __restrict__ h,
    const int* __restrict__ batch, float* __restrict__ psum, int* __restrict__ pcnt) {
  int stride = gridDim.x * 256;
  for (int i = blockIdx.x * 256 + threadIdx.x; i < NN * HD; i += stride) {
    int n = i >> 7, c = i & 127;
    int g = batch[n];
    atomicAdd(&psum[g * HD + c], h[i]);
    if (c == 0) atomicAdd(&pcnt[g], 1);
  }
}

// ---------------- head ----------------
__global__ __launch_bounds__(128) void k_head(const float* __restrict__ psum,
    const int* __restrict__ pcnt, const float* __restrict__ linW,
    const float* __restrict__ linb, const float* __restrict__ outW,
    const float* __restrict__ outb, float* __restrict__ out) {
  __shared__ float pl[HD];
  __shared__ float red[2];
  int g = blockIdx.x, t = threadIdx.x;
  float cnt = fmaxf((float)pcnt[g], 1.f);
  pl[t] = psum[g * HD + t] / cnt;
  __syncthreads();
  float acc = linb[t];
  for (int k = 0; k < HD; ++k) acc = fmaf(pl[k], linW[k * HD + t], acc);
  float term = softplusf_(acc) * outW[t];
#pragma unroll
  for (int off = 32; off > 0; off >>= 1) term += __shfl_down(term, off, 64);
  if ((t & 63) == 0) red[t >> 6] = term;
  __syncthreads();
  if (t == 0) out[g] = red[0] + red[1] + outb[0];
}

extern "C" void kernel_launch(void* const* d_in, const int* in_sizes, int n_in,
                              void* d_out, int out_size, void* d_ws, size_t ws_size,
                              hipStream_t stream) {
  const float* x = (const float*)d_in[0];
  const int* ei = (const int*)d_in[1];
  const float* ea = (const float*)d_in[2];
  const int* batch = (const int*)d_in[3];
  const float* embW = (const float*)d_in[4];
  const float* embb = (const float*)d_in[5];
  const float* convW = (const float*)d_in[6];
  const float* convb = (const float*)d_in[7];
  const float* big = (const float*)d_in[8];
  const float* bib = (const float*)d_in[9];
  const float* bog = (const float*)d_in[10];
  const float* bob = (const float*)d_in[11];
  const float* linW = (const float*)d_in[12];
  const float* linb = (const float*)d_in[13];
  const float* outW = (const float*)d_in[14];
  const float* outb = (const float*)d_in[15];
  float* out = (float*)d_out;

  float* wsf = (float*)d_ws;
  size_t off = 0;
  auto alloc = [&](size_t n) {
    float* p = wsf + off;
    off += (n + 3) & ~(size_t)3;  // keep 16B alignment
    return p;
  };
  float* h0 = alloc((size_t)NN * HD);
  float* h1 = alloc((size_t)NN * HD);
  float* P1 = alloc((size_t)NN * C2);
  float* P3 = alloc((size_t)NN * C2);
  float* agg = alloc((size_t)NN * HD);
  float* st_i = alloc(2 * C2);
  float* bnsi = alloc(2 * C2);
  float* st_o = alloc(2 * HD);
  float* bnso = alloc(2 * HD);
  float* psum = alloc((size_t)NG * HD);
  int* pcnt = (int*)alloc(NG);
  int* deg = (int*)alloc(NN);
  int* cursor = (int*)alloc(NN);
  int* eid = (int*)alloc(NE);
  int* ssort = (int*)alloc(NE);
  int* dsort = (int*)alloc(NE);
  unsigned short* Wswz = (unsigned short*)alloc((NC * WSZ_L + 1) / 2);

  const int* srcp = ei;
  const int* dstp = ei + NE;

  // CSR build
  hipMemsetAsync(deg, 0, NN * sizeof(int), stream);
  k_hist<<<2048, 256, 0, stream>>>(srcp, deg);
  k_scan<<<1, 1024, 0, stream>>>(deg, cursor);
  k_scatter<<<2048, 256, 0, stream>>>(srcp, dstp, cursor, eid, ssort, dsort);

  k_wprep<<<(NC * WSZ_L + 255) / 256, 256, 0, stream>>>(convW, Wswz);
  k_embed<<<NN / 2, 256, 0, stream>>>(x, embW, embb, h0);

  float* hc = h0;
  float* hn = h1;
  for (int L = 0; L < NC; ++L) {
    const unsigned short* Wl = Wswz + (size_t)L * WSZ_L;
    const float* bL = convb + (size_t)L * C2;
    hipMemsetAsync(st_i, 0, 2 * C2 * sizeof(float), stream);
    hipMemsetAsync(st_o, 0, 2 * HD * sizeof(float), stream);
    hipMemsetAsync(agg, 0, (size_t)NN * HD * sizeof(float), stream);

    k_nodeproj<<<NN / 8, 256, 0, stream>>>(hc, convW + (size_t)L * IND * C2, P1, P3);
    k_estat<<<2500, 256, 0, stream>>>(eid, ssort, dsort, ea, Wl, bL,
        (const float4*)P1, (const float4*)P3, st_i);
    k_bnfin<<<1, 256, 0, stream>>>(st_i, 1.f / NE, big + L * C2, bib + L * C2, C2, bnsi);
    k_eapply<<<2500, 256, 0, stream>>>(eid, ssort, dsort, ea, Wl, bL,
        (const float4*)P1, (const float4*)P3, bnsi, agg);
    k_aggstat<<<512, 256, 0, stream>>>(agg, st_o);
    k_bnfin<<<1, 256, 0, stream>>>(st_o, 1.f / NN, bog + L * HD, bob + L * HD, HD, bnso);
    k_update<<<2048, 256, 0, stream>>>(hc, agg, bnso, hn);
    float* tmp = hc; hc = hn; hn = tmp;
  }

  hipMemsetAsync(psum, 0, (size_t)NG * HD * sizeof(float), stream);
  hipMemsetAsync(pcnt, 0, NG * sizeof(int), stream);
  k_pool<<<2048, 256, 0, stream>>>(hc, batch, psum, pcnt);
  k_head<<<NG, 128, 0, stream>>>(psum, pcnt, linW, linb, outW, outb, out);
}

// Round 4
// 3353.048 us; speedup vs baseline: 2.0615x; 1.3991x over previous
//
#include <hip/hip_runtime.h>

constexpr int NN = 50000;
constexpr int NE = 800000;
constexpr int XD = 92;
constexpr int ED = 80;
constexpr int HD = 128;
constexpr int C2 = 256;   // 2*HD
constexpr int IND = 336;  // 2*HD + ED
constexpr int NC = 3;
constexpr int NG = 256;
constexpr int NTILES = NE / 64;      // 12500
constexpr int WSZ_L = 16 * 3 * 64 * 8;  // per-layer swizzled W2: 24576 ushort

#define DINL __device__ __forceinline__

typedef __attribute__((ext_vector_type(8))) short bf16x8;
typedef __attribute__((ext_vector_type(4))) float f32x4;

DINL float sigmoidf_(float x) { return 1.f / (1.f + __expf(-x)); }
DINL float softplusf_(float x) { return x > 20.f ? x : log1pf(__expf(x)); }
DINL short f2bf(float f) {
  unsigned u = __float_as_uint(f);
  u = (u + 0x7fffu + ((u >> 16) & 1u)) >> 16;
  return (short)u;
}
DINL float bf2f(unsigned short u) { return __uint_as_float(((unsigned)u) << 16); }

// ---------------- embed ----------------
__global__ __launch_bounds__(256) void k_embed(const float* __restrict__ x,
    const float* __restrict__ W, const float* __restrict__ b, float* __restrict__ h) {
  __shared__ float xs[2][XD];
  int t = threadIdx.x;
  int n0 = blockIdx.x * 2;
  for (int i = t; i < 2 * XD; i += 256) xs[i / XD][i % XD] = x[(size_t)n0 * XD + i];
  __syncthreads();
  int lo = t >> 7, c = t & 127;
  float acc = b[c];
  for (int k = 0; k < XD; ++k) acc = fmaf(xs[lo][k], W[k * HD + c], acc);
  h[(size_t)(n0 + lo) * HD + c] = acc;
}

// ---------------- node projections ----------------
__global__ __launch_bounds__(256) void k_nodeproj(const float* __restrict__ h,
    const float* __restrict__ W, float* __restrict__ P1, float* __restrict__ P3) {
  __shared__ float hs[8][HD];
  int t = threadIdx.x;
  int n0 = blockIdx.x * 8;
  for (int i = t; i < 8 * HD; i += 256) hs[i >> 7][i & 127] = h[(size_t)n0 * HD + i];
  __syncthreads();
  float a1[8], a3[8];
#pragma unroll
  for (int n = 0; n < 8; ++n) { a1[n] = 0.f; a3[n] = 0.f; }
  const float* W1 = W;
  const float* W3 = W + 208 * C2;
  for (int k = 0; k < HD; ++k) {
    float w1 = W1[k * C2 + t], w3 = W3[k * C2 + t];
#pragma unroll
    for (int n = 0; n < 8; ++n) {
      a1[n] = fmaf(hs[n][k], w1, a1[n]);
      a3[n] = fmaf(hs[n][k], w3, a3[n]);
    }
  }
#pragma unroll
  for (int n = 0; n < 8; ++n) {
    P1[(size_t)(n0 + n) * C2 + t] = a1[n];
    P3[(size_t)(n0 + n) * C2 + t] = a3[n];
  }
}

// ---------------- CSR build ----------------
__global__ __launch_bounds__(256) void k_hist(const int* __restrict__ src,
                                              int* __restrict__ deg) {
  for (int e = blockIdx.x * 256 + threadIdx.x; e < NE; e += gridDim.x * 256)
    atomicAdd(&deg[src[e]], 1);
}

__global__ __launch_bounds__(1024) void k_scan(const int* __restrict__ deg,
                                               int* __restrict__ cursor) {
  __shared__ int sums[1024];
  int t = threadIdx.x;
  const int CH = 49;
  int b0 = t * CH;
  int s = 0;
  for (int i = 0; i < CH; ++i) {
    int idx = b0 + i;
    if (idx < NN) s += deg[idx];
  }
  sums[t] = s;
  __syncthreads();
  for (int off = 1; off < 1024; off <<= 1) {
    int v = (t >= off) ? sums[t - off] : 0;
    __syncthreads();
    sums[t] += v;
    __syncthreads();
  }
  int excl = (t == 0) ? 0 : sums[t - 1];
  for (int i = 0; i < CH; ++i) {
    int idx = b0 + i;
    if (idx < NN) {
      cursor[idx] = excl;
      excl += deg[idx];
    }
  }
}

__global__ __launch_bounds__(256) void k_scatter(const int* __restrict__ src,
    const int* __restrict__ dst, int* __restrict__ cursor, int* __restrict__ eid,
    int* __restrict__ ssort, int* __restrict__ dsort) {
  for (int e = blockIdx.x * 256 + threadIdx.x; e < NE; e += gridDim.x * 256) {
    int s = src[e];
    int pos = atomicAdd(&cursor[s], 1);
    eid[pos] = e;
    ssort[pos] = s;
    dsort[pos] = dst[e];
  }
}

// ---------------- W2 -> MFMA fragment pre-swizzle ----------------
__global__ __launch_bounds__(256) void k_wprep(const float* __restrict__ convW,
                                               unsigned short* __restrict__ Wswz) {
  int idx = blockIdx.x * 256 + threadIdx.x;
  if (idx >= NC * WSZ_L) return;
  int L = idx / WSZ_L;
  int rem = idx - L * WSZ_L;
  int mt = rem / 1536;
  int rem2 = rem - mt * 1536;
  int ks = rem2 >> 9;
  int lane = (rem2 >> 3) & 63;
  int j = rem2 & 7;
  int k = ks * 32 + (lane >> 4) * 8 + j;
  int m = mt * 16 + (lane & 15);
  float v = (k < ED) ? convW[(size_t)L * IND * C2 + (size_t)(HD + k) * C2 + m] : 0.f;
  Wswz[idx] = (unsigned short)f2bf(v);
}

// ---------------- ea -> CSR-ordered MFMA B-fragment layout (once per call) ----------------
// eaf[(tile*12 + nt*3+ks)*64 + l] : lane l=16g+c holds edge (tile*64+nt*16+c), k=ks*32+g*8..+7
__global__ __launch_bounds__(256) void k_eaprep(const int* __restrict__ eid,
    const float* __restrict__ ea, bf16x8* __restrict__ eaf) {
  int idx = blockIdx.x * 256 + threadIdx.x;
  if (idx >= NTILES * 768) return;
  int tile = idx / 768;
  int r = idx - tile * 768;
  int fr = r >> 6, l = r & 63;
  int nt = fr / 3, ks = fr - 3 * nt;
  int c = l & 15, g = l >> 4;
  int k0 = ks * 32 + g * 8;
  bf16x8 v;
  if (k0 < ED) {
    int e = eid[tile * 64 + nt * 16 + c];
    const float* p = ea + (size_t)e * ED + k0;
    float4 x0 = *(const float4*)p;
    float4 x1 = *(const float4*)(p + 4);
    v[0] = f2bf(x0.x); v[1] = f2bf(x0.y); v[2] = f2bf(x0.z); v[3] = f2bf(x0.w);
    v[4] = f2bf(x1.x); v[5] = f2bf(x1.y); v[6] = f2bf(x1.z); v[7] = f2bf(x1.w);
  } else {
#pragma unroll
    for (int j = 0; j < 8; ++j) v[j] = 0;
  }
  eaf[idx] = v;
}

// ---------------- FULL PATH pass 1: MFMA + gather + stats + msg(bf16) store ----------------
// no LDS, no barriers. wave w owns m-tiles {2w,2w+1,2w+8,2w+9}; lane 16g+c.
__global__ __launch_bounds__(256) void k_estat2(
    const int* __restrict__ ssort, const int* __restrict__ dsort,
    const bf16x8* __restrict__ eaf, const unsigned short* __restrict__ Wswz,
    const float* __restrict__ bias, const float4* __restrict__ P14,
    const float4* __restrict__ P34, ushort4* __restrict__ msgc,
    float* __restrict__ stats) {
  int t = threadIdx.x;
  int w = t >> 6, l = t & 63;
  int g = l >> 4, c = l & 15;
  int mtg[4] = {2 * w, 2 * w + 1, 2 * w + 8, 2 * w + 9};
  const bf16x8* Wf = (const bf16x8*)Wswz;
  bf16x8 af[4][3];
  f32x4 bias4[4];
#pragma unroll
  for (int m = 0; m < 4; ++m) {
#pragma unroll
    for (int ks = 0; ks < 3; ++ks) af[m][ks] = Wf[(mtg[m] * 3 + ks) * 64 + l];
    float4 bb = ((const float4*)bias)[mtg[m] * 4 + g];
    bias4[m][0] = bb.x; bias4[m][1] = bb.y; bias4[m][2] = bb.z; bias4[m][3] = bb.w;
  }
  f32x4 ssum[4], ssq[4];
#pragma unroll
  for (int m = 0; m < 4; ++m)
#pragma unroll
    for (int i = 0; i < 4; ++i) { ssum[m][i] = 0.f; ssq[m][i] = 0.f; }

  for (int tile = blockIdx.x; tile < NTILES; tile += gridDim.x) {
    int e0 = tile * 64;
#pragma unroll
    for (int nt = 0; nt < 4; ++nt) {
      const bf16x8* bp = eaf + ((size_t)tile * 12 + nt * 3) * 64 + l;
      bf16x8 b0 = bp[0];
      bf16x8 b1 = bp[64];
      bf16x8 b2 = bp[128];
      f32x4 acc[4];
#pragma unroll
      for (int m = 0; m < 4; ++m) {
        acc[m][0] = 0.f; acc[m][1] = 0.f; acc[m][2] = 0.f; acc[m][3] = 0.f;
      }
#pragma unroll
      for (int m = 0; m < 4; ++m)
        acc[m] = __builtin_amdgcn_mfma_f32_16x16x32_bf16(af[m][0], b0, acc[m], 0, 0, 0);
#pragma unroll
      for (int m = 0; m < 4; ++m)
        acc[m] = __builtin_amdgcn_mfma_f32_16x16x32_bf16(af[m][1], b1, acc[m], 0, 0, 0);
#pragma unroll
      for (int m = 0; m < 4; ++m)
        acc[m] = __builtin_amdgcn_mfma_f32_16x16x32_bf16(af[m][2], b2, acc[m], 0, 0, 0);
      int s_ = ssort[e0 + nt * 16 + c];
      int d_ = dsort[e0 + nt * 16 + c];
#pragma unroll
      for (int m = 0; m < 4; ++m) {
        float4 p1 = P14[(size_t)s_ * 64 + mtg[m] * 4 + g];
        float4 p3 = P34[(size_t)d_ * 64 + mtg[m] * 4 + g];
        f32x4 ms;
        ms[0] = acc[m][0] + bias4[m][0] + p1.x + p3.x;
        ms[1] = acc[m][1] + bias4[m][1] + p1.y + p3.y;
        ms[2] = acc[m][2] + bias4[m][2] + p1.z + p3.z;
        ms[3] = acc[m][3] + bias4[m][3] + p1.w + p3.w;
#pragma unroll
        for (int i = 0; i < 4; ++i) {
          ssum[m][i] += ms[i];
          ssq[m][i] = fmaf(ms[i], ms[i], ssq[m][i]);
        }
        ushort4 st;
        st.x = (unsigned short)f2bf(ms[0]);
        st.y = (unsigned short)f2bf(ms[1]);
        st.z = (unsigned short)f2bf(ms[2]);
        st.w = (unsigned short)f2bf(ms[3]);
        msgc[(((size_t)tile * 4 + nt) * 16 + w * 4 + m) * 64 + l] = st;
      }
    }
  }
#pragma unroll
  for (int off = 1; off < 16; off <<= 1)
#pragma unroll
    for (int m = 0; m < 4; ++m)
#pragma unroll
      for (int i = 0; i < 4; ++i) {
        ssum[m][i] += __shfl_xor(ssum[m][i], off, 16);
        ssq[m][i] += __shfl_xor(ssq[m][i], off, 16);
      }
  if (c == 0) {
#pragma unroll
    for (int m = 0; m < 4; ++m)
#pragma unroll
      for (int i = 0; i < 4; ++i) {
        int ch = mtg[m] * 16 + 4 * g + i;
        atomicAdd(&stats[ch], ssum[m][i]);
        atomicAdd(&stats[C2 + ch], ssq[m][i]);
      }
  }
}

// ---------------- FULL PATH pass 2: stream msg + BN + gate + segmented scatter ----------------
__global__ __launch_bounds__(256) void k_apply2(
    const int* __restrict__ ssort, const ushort4* __restrict__ msgc,
    const float* __restrict__ bns, float* __restrict__ agg) {
  int t = threadIdx.x;
  int w = t >> 6, l = t & 63;
  int g = l >> 4, c = l & 15;
  int mtg[4] = {2 * w, 2 * w + 1, 2 * w + 8, 2 * w + 9};
  f32x4 sc4[4], sh4[4];
#pragma unroll
  for (int m = 0; m < 4; ++m) {
    float4 s1 = ((const float4*)bns)[mtg[m] * 4 + g];
    float4 s2 = ((const float4*)bns)[64 + mtg[m] * 4 + g];
    sc4[m][0] = s1.x; sc4[m][1] = s1.y; sc4[m][2] = s1.z; sc4[m][3] = s1.w;
    sh4[m][0] = s2.x; sh4[m][1] = s2.y; sh4[m][2] = s2.z; sh4[m][3] = s2.w;
  }
  for (int tile = blockIdx.x; tile < NTILES; tile += gridDim.x) {
    int e0 = tile * 64;
#pragma unroll
    for (int nt = 0; nt < 4; ++nt) {
      int s_ = ssort[e0 + nt * 16 + c];
      int ps = __shfl_up(s_, 1, 16);
      bool head = (c == 0) || (ps != s_);
      int hp = head ? c : 0;
#pragma unroll
      for (int dd = 1; dd < 16; dd <<= 1) {
        int t2 = __shfl_up(hp, dd, 16);
        if (c >= dd) hp = max(hp, t2);
      }
      int ns = __shfl_down(s_, 1, 16);
      bool tail = (c == 15) || (ns != s_);
      f32x4 v4[4];
#pragma unroll
      for (int m = 0; m < 4; ++m) {
        ushort4 mw = msgc[(((size_t)tile * 4 + nt) * 16 + w * 4 + m) * 64 + l];
        v4[m][0] = fmaf(bf2f(mw.x), sc4[m][0], sh4[m][0]);
        v4[m][1] = fmaf(bf2f(mw.y), sc4[m][1], sh4[m][1]);
        v4[m][2] = fmaf(bf2f(mw.z), sc4[m][2], sh4[m][2]);
        v4[m][3] = fmaf(bf2f(mw.w), sc4[m][3], sh4[m][3]);
      }
      float gg_[8];
#pragma unroll
      for (int p = 0; p < 2; ++p)
#pragma unroll
        for (int i = 0; i < 4; ++i)
          gg_[p * 4 + i] = sigmoidf_(v4[p][i]) * softplusf_(v4[p + 2][i]);
#pragma unroll
      for (int dd = 1; dd < 16; dd <<= 1) {
#pragma unroll
        for (int q = 0; q < 8; ++q) {
          float tv = __shfl_up(gg_[q], dd, 16);
          if (c - dd >= hp) gg_[q] += tv;
        }
      }
      if (tail) {
#pragma unroll
        for (int p = 0; p < 2; ++p)
#pragma unroll
          for (int i = 0; i < 4; ++i)
            atomicAdd(&agg[(size_t)s_ * HD + mtg[p] * 16 + 4 * g + i], gg_[p * 4 + i]);
      }
    }
  }
}

// ================= R3 FALLBACK PATH (used only if ws too small) =================
DINL void stage_tile(int t, int e0, const int* eid, const int* ssort, const int* dsort,
                     const float* __restrict__ ea, int* ei_, int* se, int* de,
                     bf16x8* Bls) {
  if (t < 64) ei_[t] = eid[e0 + t];
  else if (t < 128) se[t - 64] = ssort[e0 + t - 64];
  else if (t < 192) de[t - 128] = dsort[e0 + t - 128];
  __syncthreads();
  for (int i = t; i < 768; i += 256) {
    int fl = i & 63;
    int fr = i >> 6;
    int nt = fr / 3, ks = fr - 3 * nt;
    int rr = fl & 15, gg = fl >> 4;
    int k0 = ks * 32 + gg * 8;
    bf16x8 v;
    if (k0 < ED) {
      const float* p = ea + (size_t)ei_[nt * 16 + rr] * ED + k0;
      float4 x0 = *(const float4*)p;
      float4 x1 = *(const float4*)(p + 4);
      v[0] = f2bf(x0.x); v[1] = f2bf(x0.y); v[2] = f2bf(x0.z); v[3] = f2bf(x0.w);
      v[4] = f2bf(x1.x); v[5] = f2bf(x1.y); v[6] = f2bf(x1.z); v[7] = f2bf(x1.w);
    } else {
#pragma unroll
      for (int j = 0; j < 8; ++j) v[j] = 0;
    }
    Bls[fr * 64 + fl] = v;
  }
  __syncthreads();
}

__global__ __launch_bounds__(256) void k_estat(
    const int* __restrict__ eid, const int* __restrict__ ssort, const int* __restrict__ dsort,
    const float* __restrict__ ea, const unsigned short* __restrict__ Wswz,
    const float* __restrict__ bias, const float4* __restrict__ P14,
    const float4* __restrict__ P34, float* __restrict__ stats) {
  __shared__ bf16x8 Bls[768];
  __shared__ int ei_[64], se[64], de[64];
  int t = threadIdx.x;
  int w = t >> 6, l = t & 63;
  int g = l >> 4, c = l & 15;
  int mtg[4] = {2 * w, 2 * w + 1, 2 * w + 8, 2 * w + 9};
  const bf16x8* Wf = (const bf16x8*)Wswz;
  bf16x8 af[4][3];
  f32x4 bias4[4];
#pragma unroll
  for (int m = 0; m < 4; ++m) {
#pragma unroll
    for (int ks = 0; ks < 3; ++ks) af[m][ks] = Wf[(mtg[m] * 3 + ks) * 64 + l];
    float4 bb = ((const float4*)bias)[mtg[m] * 4 + g];
    bias4[m][0] = bb.x; bias4[m][1] = bb.y; bias4[m][2] = bb.z; bias4[m][3] = bb.w;
  }
  f32x4 ssum[4], ssq[4];
#pragma unroll
  for (int m = 0; m < 4; ++m)
#pragma unroll
    for (int i = 0; i < 4; ++i) { ssum[m][i] = 0.f; ssq[m][i] = 0.f; }

  for (int tile = blockIdx.x; tile < NTILES; tile += gridDim.x) {
    stage_tile(t, tile * 64, eid, ssort, dsort, ea, ei_, se, de, Bls);
    f32x4 acc[4][4];
#pragma unroll
    for (int m = 0; m < 4; ++m)
#pragma unroll
      for (int n = 0; n < 4; ++n)
#pragma unroll
        for (int i = 0; i < 4; ++i) acc[m][n][i] = 0.f;
#pragma unroll
    for (int nt = 0; nt < 4; ++nt)
#pragma unroll
      for (int ks = 0; ks < 3; ++ks) {
        bf16x8 bfrag = Bls[(nt * 3 + ks) * 64 + l];
#pragma unroll
        for (int m = 0; m < 4; ++m)
          acc[m][nt] = __builtin_amdgcn_mfma_f32_16x16x32_bf16(af[m][ks], bfrag,
                                                               acc[m][nt], 0, 0, 0);
      }
#pragma unroll
    for (int nt = 0; nt < 4; ++nt) {
      int s_ = se[nt * 16 + c], d_ = de[nt * 16 + c];
#pragma unroll
      for (int m = 0; m < 4; ++m) {
        float4 p1 = P14[(size_t)s_ * 64 + mtg[m] * 4 + g];
        float4 p3 = P34[(size_t)d_ * 64 + mtg[m] * 4 + g];
        f32x4 ms;
        ms[0] = acc[m][nt][0] + bias4[m][0] + p1.x + p3.x;
        ms[1] = acc[m][nt][1] + bias4[m][1] + p1.y + p3.y;
        ms[2] = acc[m][nt][2] + bias4[m][2] + p1.z + p3.z;
        ms[3] = acc[m][nt][3] + bias4[m][3] + p1.w + p3.w;
#pragma unroll
        for (int i = 0; i < 4; ++i) {
          ssum[m][i] += ms[i];
          ssq[m][i] = fmaf(ms[i], ms[i], ssq[m][i]);
        }
      }
    }
    __syncthreads();
  }
#pragma unroll
  for (int off = 1; off < 16; off <<= 1)
#pragma unroll
    for (int m = 0; m < 4; ++m)
#pragma unroll
      for (int i = 0; i < 4; ++i) {
        ssum[m][i] += __shfl_xor(ssum[m][i], off, 16);
        ssq[m][i] += __shfl_xor(ssq[m][i], off, 16);
      }
  if (c == 0) {
#pragma unroll
    for (int m = 0; m < 4; ++m)
#pragma unroll
      for (int i = 0; i < 4; ++i) {
        int ch = mtg[m] * 16 + 4 * g + i;
        atomicAdd(&stats[ch], ssum[m][i]);
        atomicAdd(&stats[C2 + ch], ssq[m][i]);
      }
  }
}

__global__ __launch_bounds__(256) void k_eapply(
    const int* __restrict__ eid, const int* __restrict__ ssort, const int* __restrict__ dsort,
    const float* __restrict__ ea, const unsigned short* __restrict__ Wswz,
    const float* __restrict__ bias, const float4* __restrict__ P14,
    const float4* __restrict__ P34, const float* __restrict__ bns,
    float* __restrict__ agg) {
  __shared__ bf16x8 Bls[768];
  __shared__ int ei_[64], se[64], de[64];
  int t = threadIdx.x;
  int w = t >> 6, l = t & 63;
  int g = l >> 4, c = l & 15;
  int mtg[4] = {2 * w, 2 * w + 1, 2 * w + 8, 2 * w + 9};
  const bf16x8* Wf = (const bf16x8*)Wswz;
  bf16x8 af[4][3];
  f32x4 bias4[4], sc4[4], sh4[4];
#pragma unroll
  for (int m = 0; m < 4; ++m) {
#pragma unroll
    for (int ks = 0; ks < 3; ++ks) af[m][ks] = Wf[(mtg[m] * 3 + ks) * 64 + l];
    float4 bb = ((const float4*)bias)[mtg[m] * 4 + g];
    float4 s1 = ((const float4*)bns)[mtg[m] * 4 + g];
    float4 s2 = ((const float4*)bns)[64 + mtg[m] * 4 + g];
    bias4[m][0] = bb.x; bias4[m][1] = bb.y; bias4[m][2] = bb.z; bias4[m][3] = bb.w;
    sc4[m][0] = s1.x; sc4[m][1] = s1.y; sc4[m][2] = s1.z; sc4[m][3] = s1.w;
    sh4[m][0] = s2.x; sh4[m][1] = s2.y; sh4[m][2] = s2.z; sh4[m][3] = s2.w;
  }
  for (int tile = blockIdx.x; tile < NTILES; tile += gridDim.x) {
    stage_tile(t, tile * 64, eid, ssort, dsort, ea, ei_, se, de, Bls);
    f32x4 acc[4][4];
#pragma unroll
    for (int m = 0; m < 4; ++m)
#pragma unroll
      for (int n = 0; n < 4; ++n)
#pragma unroll
        for (int i = 0; i < 4; ++i) acc[m][n][i] = 0.f;
#pragma unroll
    for (int nt = 0; nt < 4; ++nt)
#pragma unroll
      for (int ks = 0; ks < 3; ++ks) {
        bf16x8 bfrag = Bls[(nt * 3 + ks) * 64 + l];
#pragma unroll
        for (int m = 0; m < 4; ++m)
          acc[m][nt] = __builtin_amdgcn_mfma_f32_16x16x32_bf16(af[m][ks], bfrag,
                                                               acc[m][nt], 0, 0, 0);
      }
#pragma unroll
    for (int nt = 0; nt < 4; ++nt) {
      int s_ = se[nt * 16 + c], d_ = de[nt * 16 + c];
      int ps = __shfl_up(s_, 1, 16);
      bool head = (c == 0) || (ps != s_);
      int hp = head ? c : 0;
#pragma unroll
      for (int dd = 1; dd < 16; dd <<= 1) {
        int t2 = __shfl_up(hp, dd, 16);
        if (c >= dd) hp = max(hp, t2);
      }
      int ns = __shfl_down(s_, 1, 16);
      bool tail = (c == 15) || (ns != s_);
      f32x4 v4[4];
#pragma unroll
      for (int m = 0; m < 4; ++m) {
        float4 p1 = P14[(size_t)s_ * 64 + mtg[m] * 4 + g];
        float4 p3 = P34[(size_t)d_ * 64 + mtg[m] * 4 + g];
        v4[m][0] = fmaf(acc[m][nt][0] + bias4[m][0] + p1.x + p3.x, sc4[m][0], sh4[m][0]);
        v4[m][1] = fmaf(acc[m][nt][1] + bias4[m][1] + p1.y + p3.y, sc4[m][1], sh4[m][1]);
        v4[m][2] = fmaf(acc[m][nt][2] + bias4[m][2] + p1.z + p3.z, sc4[m][2], sh4[m][2]);
        v4[m][3] = fmaf(acc[m][nt][3] + bias4[m][3] + p1.w + p3.w, sc4[m][3], sh4[m][3]);
      }
      float gg_[8];
#pragma unroll
      for (int p = 0; p < 2; ++p)
#pragma unroll
        for (int i = 0; i < 4; ++i)
          gg_[p * 4 + i] = sigmoidf_(v4[p][i]) * softplusf_(v4[p + 2][i]);
#pragma unroll
      for (int dd = 1; dd < 16; dd <<= 1) {
#pragma unroll
        for (int q = 0; q < 8; ++q) {
          float tv = __shfl_up(gg_[q], dd, 16);
          if (c - dd >= hp) gg_[q] += tv;
        }
      }
      if (tail) {
#pragma unroll
        for (int p = 0; p < 2; ++p)
#pragma unroll
          for (int i = 0; i < 4; ++i)
            atomicAdd(&agg[(size_t)s_ * HD + mtg[p] * 16 + 4 * g + i], gg_[p * 4 + i]);
      }
    }
    __syncthreads();
  }
}
// ================= end fallback =================

// ---------------- finalize BN ----------------
__global__ void k_bnfin(const float* __restrict__ stats, float invcount,
                        const float* __restrict__ gamma, const float* __restrict__ beta,
                        int nch, float* __restrict__ out) {
  int t = blockIdx.x * blockDim.x + threadIdx.x;
  if (t < nch) {
    float mean = stats[t] * invcount;
    float var = stats[nch + t] * invcount - mean * mean;
    float istd = rsqrtf(var + 1e-5f);
    float sc = gamma[t] * istd;
    out[t] = sc;
    out[nch + t] = beta[t] - mean * sc;
  }
}

// ---------------- agg BN stats ----------------
__global__ __launch_bounds__(256) void k_aggstat(const float* __restrict__ agg,
                                                 float* __restrict__ stats) {
  int t = threadIdx.x;
  int c = t & 127, half = t >> 7;
  float s = 0.f, sq = 0.f;
  for (int n = blockIdx.x * 2 + half; n < NN; n += gridDim.x * 2) {
    float v = agg[(size_t)n * HD + c];
    s += v;
    sq = fmaf(v, v, sq);
  }
  __shared__ float shs[2][128], shq[2][128];
  shs[half][c] = s;
  shq[half][c] = sq;
  __syncthreads();
  if (t < 128) {
    atomicAdd(&stats[c], shs[0][c] + shs[1][c]);
    atomicAdd(&stats[128 + c], shq[0][c] + shq[1][c]);
  }
}

// ---------------- h update ----------------
__global__ __launch_bounds__(256) void k_update(const float* __restrict__ h,
    const float* __restrict__ agg, const float* __restrict__ bns, float* __restrict__ hn) {
  int stride = gridDim.x * 256;
  for (int i = blockIdx.x * 256 + threadIdx.x; i < NN * HD; i += stride) {
    int c = i & 127;
    float v = h[i] + fmaf(agg[i], bns[c], bns[128 + c]);
    hn[i] = softplusf_(v);
  }
}

// ---------------- pooling ----------------
__global__ __launch_bounds__(256) void k_pool(const float* __restrict__ h,
    const int* __restrict__ batch, float* __restrict__ psum, int* __restrict__ pcnt) {
  int stride = gridDim.x * 256;
  for (int i = blockIdx.x * 256 + threadIdx.x; i < NN * HD; i += stride) {
    int n = i >> 7, c = i & 127;
    int g = batch[n];
    atomicAdd(&psum[g * HD + c], h[i]);
    if (c == 0) atomicAdd(&pcnt[g], 1);
  }
}

// ---------------- head ----------------
__global__ __launch_bounds__(128) void k_head(const float* __restrict__ psum,
    const int* __restrict__ pcnt, const float* __restrict__ linW,
    const float* __restrict__ linb, const float* __restrict__ outW,
    const float* __restrict__ outb, float* __restrict__ out) {
  __shared__ float pl[HD];
  __shared__ float red[2];
  int g = blockIdx.x, t = threadIdx.x;
  float cnt = fmaxf((float)pcnt[g], 1.f);
  pl[t] = psum[g * HD + t] / cnt;
  __syncthreads();
  float acc = linb[t];
  for (int k = 0; k < HD; ++k) acc = fmaf(pl[k], linW[k * HD + t], acc);
  float term = softplusf_(acc) * outW[t];
#pragma unroll
  for (int off = 32; off > 0; off >>= 1) term += __shfl_down(term, off, 64);
  if ((t & 63) == 0) red[t >> 6] = term;
  __syncthreads();
  if (t == 0) out[g] = red[0] + red[1] + outb[0];
}

extern "C" void kernel_launch(void* const* d_in, const int* in_sizes, int n_in,
                              void* d_out, int out_size, void* d_ws, size_t ws_size,
                              hipStream_t stream) {
  const float* x = (const float*)d_in[0];
  const int* ei = (const int*)d_in[1];
  const float* ea = (const float*)d_in[2];
  const int* batch = (const int*)d_in[3];
  const float* embW = (const float*)d_in[4];
  const float* embb = (const float*)d_in[5];
  const float* convW = (const float*)d_in[6];
  const float* convb = (const float*)d_in[7];
  const float* big = (const float*)d_in[8];
  const float* bib = (const float*)d_in[9];
  const float* bog = (const float*)d_in[10];
  const float* bob = (const float*)d_in[11];
  const float* linW = (const float*)d_in[12];
  const float* linb = (const float*)d_in[13];
  const float* outW = (const float*)d_in[14];
  const float* outb = (const float*)d_in[15];
  float* out = (float*)d_out;

  float* wsf = (float*)d_ws;
  size_t off = 0;
  auto alloc = [&](size_t n) {
    float* p = wsf + off;
    off += (n + 3) & ~(size_t)3;  // 16B alignment
    return p;
  };
  float* h0 = alloc((size_t)NN * HD);
  float* h1 = alloc((size_t)NN * HD);
  float* P1 = alloc((size_t)NN * C2);
  float* P3 = alloc((size_t)NN * C2);
  float* agg = alloc((size_t)NN * HD);
  float* st_i = alloc(2 * C2);
  float* bnsi = alloc(2 * C2);
  float* st_o = alloc(2 * HD);
  float* bnso = alloc(2 * HD);
  float* psum = alloc((size_t)NG * HD);
  int* pcnt = (int*)alloc(NG);
  int* deg = (int*)alloc(NN);
  int* cursor = (int*)alloc(NN);
  int* eid = (int*)alloc(NE);
  int* ssort = (int*)alloc(NE);
  int* dsort = (int*)alloc(NE);
  unsigned short* Wswz = (unsigned short*)alloc((NC * WSZ_L + 1) / 2);
  // full-path extras
  bf16x8* eaf = (bf16x8*)alloc((size_t)NTILES * 768 * 4);
  ushort4* msgc = (ushort4*)alloc((size_t)NE * C2 / 2);
  bool fullpath = (ws_size >= off * sizeof(float));

  const int* srcp = ei;
  const int* dstp = ei + NE;

  // CSR build
  hipMemsetAsync(deg, 0, NN * sizeof(int), stream);
  k_hist<<<2048, 256, 0, stream>>>(srcp, deg);
  k_scan<<<1, 1024, 0, stream>>>(deg, cursor);
  k_scatter<<<2048, 256, 0, stream>>>(srcp, dstp, cursor, eid, ssort, dsort);

  k_wprep<<<(NC * WSZ_L + 255) / 256, 256, 0, stream>>>(convW, Wswz);
  if (fullpath)
    k_eaprep<<<(NTILES * 768 + 255) / 256, 256, 0, stream>>>(eid, ea, eaf);
  k_embed<<<NN / 2, 256, 0, stream>>>(x, embW, embb, h0);

  float* hc = h0;
  float* hn = h1;
  for (int L = 0; L < NC; ++L) {
    const unsigned short* Wl = Wswz + (size_t)L * WSZ_L;
    const float* bL = convb + (size_t)L * C2;
    hipMemsetAsync(st_i, 0, 2 * C2 * sizeof(float), stream);
    hipMemsetAsync(st_o, 0, 2 * HD * sizeof(float), stream);
    hipMemsetAsync(agg, 0, (size_t)NN * HD * sizeof(float), stream);

    k_nodeproj<<<NN / 8, 256, 0, stream>>>(hc, convW + (size_t)L * IND * C2, P1, P3);
    if (fullpath) {
      k_estat2<<<2500, 256, 0, stream>>>(ssort, dsort, eaf, Wl, bL,
          (const float4*)P1, (const float4*)P3, msgc, st_i);
      k_bnfin<<<1, 256, 0, stream>>>(st_i, 1.f / NE, big + L * C2, bib + L * C2, C2, bnsi);
      k_apply2<<<2500, 256, 0, stream>>>(ssort, msgc, bnsi, agg);
    } else {
      k_estat<<<2500, 256, 0, stream>>>(eid, ssort, dsort, ea, Wl, bL,
          (const float4*)P1, (const float4*)P3, st_i);
      k_bnfin<<<1, 256, 0, stream>>>(st_i, 1.f / NE, big + L * C2, bib + L * C2, C2, bnsi);
      k_eapply<<<2500, 256, 0, stream>>>(eid, ssort, dsort, ea, Wl, bL,
          (const float4*)P1, (const float4*)P3, bnsi, agg);
    }
    k_aggstat<<<512, 256, 0, stream>>>(agg, st_o);
    k_bnfin<<<1, 256, 0, stream>>>(st_o, 1.f / NN, bog + L * HD, bob + L * HD, HD, bnso);
    k_update<<<2048, 256, 0, stream>>>(hc, agg, bnso, hn);
    float* tmp = hc; hc = hn; hn = tmp;
  }

  hipMemsetAsync(psum, 0, (size_t)NG * HD * sizeof(float), stream);
  hipMemsetAsync(pcnt, 0, NG * sizeof(int), stream);
  k_pool<<<2048, 256, 0, stream>>>(hc, batch, psum, pcnt);
  k_head<<<NG, 128, 0, stream>>>(psum, pcnt, linW, linb, outW, outb, out);
}

// Round 5
// 2668.518 us; speedup vs baseline: 2.5903x; 1.2565x over previous
//
#include <hip/hip_runtime.h>

constexpr int NN = 50000;
constexpr int NE = 800000;
constexpr int XD = 92;
constexpr int ED = 80;
constexpr int HD = 128;
constexpr int C2 = 256;   // 2*HD
constexpr int IND = 336;  // 2*HD + ED
constexpr int NC = 3;
constexpr int NG = 256;
constexpr int NTILES = NE / 64;      // 12500
constexpr int WSZ_L = 16 * 3 * 64 * 8;   // per-layer swizzled W2 frags (ushort)
constexpr int WNP_L = 16 * 4 * 64 * 8;   // per-(layer,half) nodeproj W frags = 32768 ushort

#define DINL __device__ __forceinline__

typedef __attribute__((ext_vector_type(8))) short bf16x8;
typedef __attribute__((ext_vector_type(4))) float f32x4;

DINL short f2bf(float f) {
  unsigned u = __float_as_uint(f);
  u = (u + 0x7fffu + ((u >> 16) & 1u)) >> 16;
  return (short)u;
}
DINL float bf2f(unsigned short u) { return __uint_as_float(((unsigned)u) << 16); }
DINL float rcp_(float x) {
  float r;
  asm("v_rcp_f32 %0, %1" : "=v"(r) : "v"(x));
  return r;
}
DINL float softplusf_(float x) {  // used in scalar epilogue kernels
  return x > 20.f ? x : log1pf(__expf(x));
}
// fast gate: sigmoid(f) * softplus(c)
DINL float gate_(float f, float cr) {
  float e = __expf(-f);
  float s = rcp_(1.f + e);
  float t = __expf(cr);
  float l = (cr > 15.f) ? cr : __logf(1.f + t);
  return s * l;
}

// DPP helpers (row-16 shifts, pure VALU)
template <int CTRL>
DINL int dpp_i(int old_, int src) {
  return __builtin_amdgcn_update_dpp(old_, src, CTRL, 0xF, 0xF, false);
}
template <int CTRL>
DINL float dpp_f(float old_, float src) {
  return __int_as_float(
      __builtin_amdgcn_update_dpp(__float_as_int(old_), __float_as_int(src), CTRL, 0xF, 0xF, false));
}
constexpr int SHR1 = 0x111, SHR2 = 0x112, SHR4 = 0x114, SHR8 = 0x118, SHL1 = 0x101;

// ---------------- embed: h = x @ embW + embb (also emits bf16 copy) ----------------
__global__ __launch_bounds__(256) void k_embed(const float* __restrict__ x,
    const float* __restrict__ W, const float* __restrict__ b, float* __restrict__ h,
    unsigned short* __restrict__ hbf) {
  __shared__ float xs[2][XD];
  int t = threadIdx.x;
  int n0 = blockIdx.x * 2;
  for (int i = t; i < 2 * XD; i += 256) xs[i / XD][i % XD] = x[(size_t)n0 * XD + i];
  __syncthreads();
  int lo = t >> 7, c = t & 127;
  float acc = b[c];
  for (int k = 0; k < XD; ++k) acc = fmaf(xs[lo][k], W[k * HD + c], acc);
  h[(size_t)(n0 + lo) * HD + c] = acc;
  hbf[(size_t)(n0 + lo) * HD + c] = (unsigned short)f2bf(acc);
}

// ---------------- CSR build ----------------
__global__ __launch_bounds__(256) void k_hist(const int* __restrict__ src,
                                              int* __restrict__ deg) {
  for (int e = blockIdx.x * 256 + threadIdx.x; e < NE; e += gridDim.x * 256)
    atomicAdd(&deg[src[e]], 1);
}

__global__ __launch_bounds__(1024) void k_scan(const int* __restrict__ deg,
                                               int* __restrict__ cursor) {
  __shared__ int sums[1024];
  int t = threadIdx.x;
  const int CH = 49;
  int b0 = t * CH;
  int s = 0;
  for (int i = 0; i < CH; ++i) {
    int idx = b0 + i;
    if (idx < NN) s += deg[idx];
  }
  sums[t] = s;
  __syncthreads();
  for (int off = 1; off < 1024; off <<= 1) {
    int v = (t >= off) ? sums[t - off] : 0;
    __syncthreads();
    sums[t] += v;
    __syncthreads();
  }
  int excl = (t == 0) ? 0 : sums[t - 1];
  for (int i = 0; i < CH; ++i) {
    int idx = b0 + i;
    if (idx < NN) {
      cursor[idx] = excl;
      excl += deg[idx];
    }
  }
}

__global__ __launch_bounds__(256) void k_scatter(const int* __restrict__ src,
    const int* __restrict__ dst, int* __restrict__ cursor, int* __restrict__ eid,
    int* __restrict__ ssort, int* __restrict__ dsort) {
  for (int e = blockIdx.x * 256 + threadIdx.x; e < NE; e += gridDim.x * 256) {
    int s = src[e];
    int pos = atomicAdd(&cursor[s], 1);
    eid[pos] = e;
    ssort[pos] = s;
    dsort[pos] = dst[e];
  }
}

// ---------------- W2 -> edge-GEMM MFMA fragments ----------------
__global__ __launch_bounds__(256) void k_wprep(const float* __restrict__ convW,
                                               unsigned short* __restrict__ Wswz) {
  int idx = blockIdx.x * 256 + threadIdx.x;
  if (idx >= NC * WSZ_L) return;
  int L = idx / WSZ_L;
  int rem = idx - L * WSZ_L;
  int mt = rem / 1536;
  int rem2 = rem - mt * 1536;
  int ks = rem2 >> 9;
  int lane = (rem2 >> 3) & 63;
  int j = rem2 & 7;
  int k = ks * 32 + (lane >> 4) * 8 + j;
  int m = mt * 16 + (lane & 15);
  float v = (k < ED) ? convW[(size_t)L * IND * C2 + (size_t)(HD + k) * C2 + m] : 0.f;
  Wswz[idx] = (unsigned short)f2bf(v);
}

// ---------------- W1/W3 -> nodeproj MFMA fragments ----------------
// Wn[(L*2+half)*WNP_L + ((mt*4+ks)*64 + lane)*8 + j]
__global__ __launch_bounds__(256) void k_wprep2(const float* __restrict__ convW,
                                                unsigned short* __restrict__ Wn) {
  int idx = blockIdx.x * 256 + threadIdx.x;
  if (idx >= NC * 2 * WNP_L) return;
  int Lh = idx >> 15;
  int L = Lh >> 1, half = Lh & 1;
  int rem = idx & 32767;
  int mt = rem >> 11;
  int rem2 = rem & 2047;
  int ks = rem2 >> 9;
  int lane = (rem2 >> 3) & 63;
  int j = rem2 & 7;
  int k = ks * 32 + (lane >> 4) * 8 + j;   // 0..127
  int m = mt * 16 + (lane & 15);           // 0..255
  int row = (half ? 208 : 0) + k;
  Wn[idx] = (unsigned short)f2bf(convW[(size_t)L * IND * C2 + (size_t)row * C2 + m]);
}

// ---------------- nodeproj via MFMA: P = hbf @ W{1,3}, bf16 out ----------------
// grid (ceil(NN/64), 2); block 256. D[ch][node] per 16x16 tiles.
__global__ __launch_bounds__(256) void k_nodeproj2(const unsigned short* __restrict__ hbf,
    const unsigned short* __restrict__ Wn, int L,
    ushort4* __restrict__ P1, ushort4* __restrict__ P3) {
  __shared__ bf16x8 hls[1024];      // 64 nodes x 16 chunks (16B), swizzled
  __shared__ ushort4 outls[4096];   // 64 nodes x 64 quads (8B), swizzled
  int t = threadIdx.x, w = t >> 6, l = t & 63, g = l >> 4, c = l & 15;
  int n0 = blockIdx.x * 64;
  int half = blockIdx.y;
  for (int i = t; i < 1024; i += 256) {
    int node = i >> 4, chunk = i & 15;
    int gn = n0 + node;
    if (gn >= NN) gn = NN - 1;
    bf16x8 v = *(const bf16x8*)(hbf + (size_t)gn * HD + chunk * 8);
    hls[node * 16 + (chunk ^ (node & 7))] = v;
  }
  __syncthreads();
  const bf16x8* Wf = (const bf16x8*)(Wn + ((size_t)(L * 2 + half)) * WNP_L);
  bf16x8 af[4][4];
#pragma unroll
  for (int mm = 0; mm < 4; ++mm)
#pragma unroll
    for (int ks = 0; ks < 4; ++ks) af[mm][ks] = Wf[((w * 4 + mm) * 4 + ks) * 64 + l];
  f32x4 acc[4][4];
#pragma unroll
  for (int mm = 0; mm < 4; ++mm)
#pragma unroll
    for (int nt = 0; nt < 4; ++nt)
#pragma unroll
      for (int i = 0; i < 4; ++i) acc[mm][nt][i] = 0.f;
#pragma unroll
  for (int nt = 0; nt < 4; ++nt) {
    int node = nt * 16 + c;
#pragma unroll
    for (int ks = 0; ks < 4; ++ks) {
      bf16x8 b = hls[node * 16 + ((4 * ks + g) ^ (node & 7))];
#pragma unroll
      for (int mm = 0; mm < 4; ++mm)
        acc[mm][nt] = __builtin_amdgcn_mfma_f32_16x16x32_bf16(af[mm][ks], b, acc[mm][nt], 0, 0, 0);
    }
  }
  __syncthreads();
#pragma unroll
  for (int mm = 0; mm < 4; ++mm)
#pragma unroll
    for (int nt = 0; nt < 4; ++nt) {
      int node = nt * 16 + c;
      int quad = (w * 4 + mm) * 4 + g;
      ushort4 st;
      st.x = (unsigned short)f2bf(acc[mm][nt][0]);
      st.y = (unsigned short)f2bf(acc[mm][nt][1]);
      st.z = (unsigned short)f2bf(acc[mm][nt][2]);
      st.w = (unsigned short)f2bf(acc[mm][nt][3]);
      outls[node * 64 + (quad ^ ((node & 7) << 3))] = st;
    }
  __syncthreads();
  ushort4* P = half ? P3 : P1;
  for (int i = t; i < 4096; i += 256) {
    int row = i >> 6, quad = i & 63;
    int gn = n0 + row;
    if (gn < NN) P[(size_t)gn * 64 + quad] = outls[row * 64 + (quad ^ ((row & 7) << 3))];
  }
}

// ---------------- ea -> CSR-ordered MFMA B-fragments (once per call) ----------------
__global__ __launch_bounds__(256) void k_eaprep(const int* __restrict__ eid,
    const float* __restrict__ ea, bf16x8* __restrict__ eaf) {
  int idx = blockIdx.x * 256 + threadIdx.x;
  if (idx >= NTILES * 768) return;
  int tile = idx / 768;
  int r = idx - tile * 768;
  int fr = r >> 6, l = r & 63;
  int nt = fr / 3, ks = fr - 3 * nt;
  int c = l & 15, g = l >> 4;
  int k0 = ks * 32 + g * 8;
  bf16x8 v;
  if (k0 < ED) {
    int e = eid[tile * 64 + nt * 16 + c];
    const float* p = ea + (size_t)e * ED + k0;
    float4 x0 = *(const float4*)p;
    float4 x1 = *(const float4*)(p + 4);
    v[0] = f2bf(x0.x); v[1] = f2bf(x0.y); v[2] = f2bf(x0.z); v[3] = f2bf(x0.w);
    v[4] = f2bf(x1.x); v[5] = f2bf(x1.y); v[6] = f2bf(x1.z); v[7] = f2bf(x1.w);
  } else {
#pragma unroll
    for (int j = 0; j < 8; ++j) v[j] = 0;
  }
  eaf[idx] = v;
}

// ---------------- pass 1: MFMA + bf16 gather + stats + msg(bf16) store ----------------
__global__ __launch_bounds__(256) void k_estat2(
    const int* __restrict__ ssort, const int* __restrict__ dsort,
    const bf16x8* __restrict__ eaf, const unsigned short* __restrict__ Wswz,
    const float* __restrict__ bias, const ushort4* __restrict__ P1b,
    const ushort4* __restrict__ P3b, ushort4* __restrict__ msgc,
    float* __restrict__ stats) {
  int t = threadIdx.x;
  int w = t >> 6, l = t & 63;
  int g = l >> 4, c = l & 15;
  int mtg[4] = {2 * w, 2 * w + 1, 2 * w + 8, 2 * w + 9};
  const bf16x8* Wf = (const bf16x8*)Wswz;
  bf16x8 af[4][3];
  f32x4 bias4[4];
#pragma unroll
  for (int m = 0; m < 4; ++m) {
#pragma unroll
    for (int ks = 0; ks < 3; ++ks) af[m][ks] = Wf[(mtg[m] * 3 + ks) * 64 + l];
    float4 bb = ((const float4*)bias)[mtg[m] * 4 + g];
    bias4[m][0] = bb.x; bias4[m][1] = bb.y; bias4[m][2] = bb.z; bias4[m][3] = bb.w;
  }
  f32x4 ssum[4], ssq[4];
#pragma unroll
  for (int m = 0; m < 4; ++m)
#pragma unroll
    for (int i = 0; i < 4; ++i) { ssum[m][i] = 0.f; ssq[m][i] = 0.f; }

  for (int tile = blockIdx.x; tile < NTILES; tile += gridDim.x) {
    int e0 = tile * 64;
#pragma unroll
    for (int nt = 0; nt < 4; ++nt) {
      const bf16x8* bp = eaf + ((size_t)tile * 12 + nt * 3) * 64 + l;
      bf16x8 b0 = bp[0];
      bf16x8 b1 = bp[64];
      bf16x8 b2 = bp[128];
      f32x4 acc[4];
#pragma unroll
      for (int m = 0; m < 4; ++m) {
        acc[m][0] = 0.f; acc[m][1] = 0.f; acc[m][2] = 0.f; acc[m][3] = 0.f;
      }
#pragma unroll
      for (int m = 0; m < 4; ++m)
        acc[m] = __builtin_amdgcn_mfma_f32_16x16x32_bf16(af[m][0], b0, acc[m], 0, 0, 0);
#pragma unroll
      for (int m = 0; m < 4; ++m)
        acc[m] = __builtin_amdgcn_mfma_f32_16x16x32_bf16(af[m][1], b1, acc[m], 0, 0, 0);
#pragma unroll
      for (int m = 0; m < 4; ++m)
        acc[m] = __builtin_amdgcn_mfma_f32_16x16x32_bf16(af[m][2], b2, acc[m], 0, 0, 0);
      int s_ = ssort[e0 + nt * 16 + c];
      int d_ = dsort[e0 + nt * 16 + c];
#pragma unroll
      for (int m = 0; m < 4; ++m) {
        ushort4 q1 = P1b[(size_t)s_ * 64 + mtg[m] * 4 + g];
        ushort4 q3 = P3b[(size_t)d_ * 64 + mtg[m] * 4 + g];
        f32x4 ms;
        ms[0] = acc[m][0] + bias4[m][0] + bf2f(q1.x) + bf2f(q3.x);
        ms[1] = acc[m][1] + bias4[m][1] + bf2f(q1.y) + bf2f(q3.y);
        ms[2] = acc[m][2] + bias4[m][2] + bf2f(q1.z) + bf2f(q3.z);
        ms[3] = acc[m][3] + bias4[m][3] + bf2f(q1.w) + bf2f(q3.w);
#pragma unroll
        for (int i = 0; i < 4; ++i) {
          ssum[m][i] += ms[i];
          ssq[m][i] = fmaf(ms[i], ms[i], ssq[m][i]);
        }
        ushort4 st;
        st.x = (unsigned short)f2bf(ms[0]);
        st.y = (unsigned short)f2bf(ms[1]);
        st.z = (unsigned short)f2bf(ms[2]);
        st.w = (unsigned short)f2bf(ms[3]);
        msgc[(((size_t)tile * 4 + nt) * 16 + w * 4 + m) * 64 + l] = st;
      }
    }
  }
#pragma unroll
  for (int off = 1; off < 16; off <<= 1)
#pragma unroll
    for (int m = 0; m < 4; ++m)
#pragma unroll
      for (int i = 0; i < 4; ++i) {
        ssum[m][i] += __shfl_xor(ssum[m][i], off, 16);
        ssq[m][i] += __shfl_xor(ssq[m][i], off, 16);
      }
  if (c == 0) {
#pragma unroll
    for (int m = 0; m < 4; ++m)
#pragma unroll
      for (int i = 0; i < 4; ++i) {
        int ch = mtg[m] * 16 + 4 * g + i;
        atomicAdd(&stats[ch], ssum[m][i]);
        atomicAdd(&stats[C2 + ch], ssq[m][i]);
      }
  }
}

// ---------------- finalize BN ----------------
__global__ void k_bnfin(const float* __restrict__ stats, float invcount,
                        const float* __restrict__ gamma, const float* __restrict__ beta,
                        int nch, float* __restrict__ out) {
  int t = blockIdx.x * blockDim.x + threadIdx.x;
  if (t < nch) {
    float mean = stats[t] * invcount;
    float var = stats[nch + t] * invcount - mean * mean;
    float istd = rsqrtf(var + 1e-5f);
    float sc = gamma[t] * istd;
    out[t] = sc;
    out[nch + t] = beta[t] - mean * sc;
  }
}

// ---------------- pass 2: stream msg + BN + fast gate + DPP segmented scatter ----------------
__global__ __launch_bounds__(256) void k_apply2(
    const int* __restrict__ ssort, const ushort4* __restrict__ msgc,
    const float* __restrict__ bns, float* __restrict__ agg) {
  int t = threadIdx.x;
  int w = t >> 6, l = t & 63;
  int g = l >> 4, c = l & 15;
  int mtg[4] = {2 * w, 2 * w + 1, 2 * w + 8, 2 * w + 9};
  f32x4 sc4[4], sh4[4];
#pragma unroll
  for (int m = 0; m < 4; ++m) {
    float4 s1 = ((const float4*)bns)[mtg[m] * 4 + g];
    float4 s2 = ((const float4*)bns)[64 + mtg[m] * 4 + g];
    sc4[m][0] = s1.x; sc4[m][1] = s1.y; sc4[m][2] = s1.z; sc4[m][3] = s1.w;
    sh4[m][0] = s2.x; sh4[m][1] = s2.y; sh4[m][2] = s2.z; sh4[m][3] = s2.w;
  }
  for (int tile = blockIdx.x; tile < NTILES; tile += gridDim.x) {
    int e0 = tile * 64;
#pragma unroll
    for (int nt = 0; nt < 4; ++nt) {
      int s_ = ssort[e0 + nt * 16 + c];
      // segment structure across 16-lane rows (pure DPP, no LDS)
      int ps = dpp_i<SHR1>(-1, s_);
      int hp = (ps != s_) ? c : 0;
      hp = max(hp, dpp_i<SHR1>(0, hp));
      hp = max(hp, dpp_i<SHR2>(0, hp));
      hp = max(hp, dpp_i<SHR4>(0, hp));
      hp = max(hp, dpp_i<SHR8>(0, hp));
      int ns = dpp_i<SHL1>(-1, s_);
      bool tail = (ns != s_);
      bool g1 = (c - 1) >= hp, g2 = (c - 2) >= hp, g4 = (c - 4) >= hp, g8 = (c - 8) >= hp;

      f32x4 v4[4];
#pragma unroll
      for (int m = 0; m < 4; ++m) {
        ushort4 mw = msgc[(((size_t)tile * 4 + nt) * 16 + w * 4 + m) * 64 + l];
        v4[m][0] = fmaf(bf2f(mw.x), sc4[m][0], sh4[m][0]);
        v4[m][1] = fmaf(bf2f(mw.y), sc4[m][1], sh4[m][1]);
        v4[m][2] = fmaf(bf2f(mw.z), sc4[m][2], sh4[m][2]);
        v4[m][3] = fmaf(bf2f(mw.w), sc4[m][3], sh4[m][3]);
      }
      float gg_[8];
#pragma unroll
      for (int p = 0; p < 2; ++p)
#pragma unroll
        for (int i = 0; i < 4; ++i)
          gg_[p * 4 + i] = gate_(v4[p][i], v4[p + 2][i]);
#pragma unroll
      for (int q = 0; q < 8; ++q) {
        float tv;
        tv = dpp_f<SHR1>(0.f, gg_[q]); gg_[q] += g1 ? tv : 0.f;
        tv = dpp_f<SHR2>(0.f, gg_[q]); gg_[q] += g2 ? tv : 0.f;
        tv = dpp_f<SHR4>(0.f, gg_[q]); gg_[q] += g4 ? tv : 0.f;
        tv = dpp_f<SHR8>(0.f, gg_[q]); gg_[q] += g8 ? tv : 0.f;
      }
      if (tail) {
#pragma unroll
        for (int p = 0; p < 2; ++p)
#pragma unroll
          for (int i = 0; i < 4; ++i)
            atomicAdd(&agg[(size_t)s_ * HD + mtg[p] * 16 + 4 * g + i], gg_[p * 4 + i]);
      }
    }
  }
}

// ---------------- agg BN stats ----------------
__global__ __launch_bounds__(256) void k_aggstat(const float* __restrict__ agg,
                                                 float* __restrict__ stats) {
  int t = threadIdx.x;
  int c = t & 127, half = t >> 7;
  float s = 0.f, sq = 0.f;
  for (int n = blockIdx.x * 2 + half; n < NN; n += gridDim.x * 2) {
    float v = agg[(size_t)n * HD + c];
    s += v;
    sq = fmaf(v, v, sq);
  }
  __shared__ float shs[2][128], shq[2][128];
  shs[half][c] = s;
  shq[half][c] = sq;
  __syncthreads();
  if (t < 128) {
    atomicAdd(&stats[c], shs[0][c] + shs[1][c]);
    atomicAdd(&stats[128 + c], shq[0][c] + shq[1][c]);
  }
}

// ---------------- h update (emits bf16 copy for next nodeproj) ----------------
__global__ __launch_bounds__(256) void k_update(const float* __restrict__ h,
    const float* __restrict__ agg, const float* __restrict__ bns, float* __restrict__ hn,
    unsigned short* __restrict__ hbf) {
  int stride = gridDim.x * 256;
  for (int i = blockIdx.x * 256 + threadIdx.x; i < NN * HD; i += stride) {
    int c = i & 127;
    float v = h[i] + fmaf(agg[i], bns[c], bns[128 + c]);
    float r = softplusf_(v);
    hn[i] = r;
    hbf[i] = (unsigned short)f2bf(r);
  }
}

// ---------------- pooling ----------------
__global__ __launch_bounds__(256) void k_pool(const float* __restrict__ h,
    const int* __restrict__ batch, float* __restrict__ psum, int* __restrict__ pcnt) {
  int stride = gridDim.x * 256;
  for (int i = blockIdx.x * 256 + threadIdx.x; i < NN * HD; i += stride) {
    int n = i >> 7, c = i & 127;
    int g = batch[n];
    atomicAdd(&psum[g * HD + c], h[i]);
    if (c == 0) atomicAdd(&pcnt[g], 1);
  }
}

// ---------------- head ----------------
__global__ __launch_bounds__(128) void k_head(const float* __restrict__ psum,
    const int* __restrict__ pcnt, const float* __restrict__ linW,
    const float* __restrict__ linb, const float* __restrict__ outW,
    const float* __restrict__ outb, float* __restrict__ out) {
  __shared__ float pl[HD];
  __shared__ float red[2];
  int g = blockIdx.x, t = threadIdx.x;
  float cnt = fmaxf((float)pcnt[g], 1.f);
  pl[t] = psum[g * HD + t] / cnt;
  __syncthreads();
  float acc = linb[t];
  for (int k = 0; k < HD; ++k) acc = fmaf(pl[k], linW[k * HD + t], acc);
  float term = softplusf_(acc) * outW[t];
#pragma unroll
  for (int off = 32; off > 0; off >>= 1) term += __shfl_down(term, off, 64);
  if ((t & 63) == 0) red[t >> 6] = term;
  __syncthreads();
  if (t == 0) out[g] = red[0] + red[1] + outb[0];
}

extern "C" void kernel_launch(void* const* d_in, const int* in_sizes, int n_in,
                              void* d_out, int out_size, void* d_ws, size_t ws_size,
                              hipStream_t stream) {
  const float* x = (const float*)d_in[0];
  const int* ei = (const int*)d_in[1];
  const float* ea = (const float*)d_in[2];
  const int* batch = (const int*)d_in[3];
  const float* embW = (const float*)d_in[4];
  const float* embb = (const float*)d_in[5];
  const float* convW = (const float*)d_in[6];
  const float* convb = (const float*)d_in[7];
  const float* big = (const float*)d_in[8];
  const float* bib = (const float*)d_in[9];
  const float* bog = (const float*)d_in[10];
  const float* bob = (const float*)d_in[11];
  const float* linW = (const float*)d_in[12];
  const float* linb = (const float*)d_in[13];
  const float* outW = (const float*)d_in[14];
  const float* outb = (const float*)d_in[15];
  float* out = (float*)d_out;

  float* wsf = (float*)d_ws;
  size_t off = 0;
  auto alloc = [&](size_t n) {
    float* p = wsf + off;
    off += (n + 3) & ~(size_t)3;  // 16B alignment
    return p;
  };
  float* h0 = alloc((size_t)NN * HD);
  float* h1 = alloc((size_t)NN * HD);
  unsigned short* hbf = (unsigned short*)alloc((size_t)NN * HD / 2);
  ushort4* P1b = (ushort4*)alloc((size_t)NN * C2 / 2);
  ushort4* P3b = (ushort4*)alloc((size_t)NN * C2 / 2);
  float* agg = alloc((size_t)NN * HD);
  float* st_i = alloc(2 * C2);
  float* bnsi = alloc(2 * C2);
  float* st_o = alloc(2 * HD);
  float* bnso = alloc(2 * HD);
  float* psum = alloc((size_t)NG * HD);
  int* pcnt = (int*)alloc(NG);
  int* deg = (int*)alloc(NN);
  int* cursor = (int*)alloc(NN);
  int* eid = (int*)alloc(NE);
  int* ssort = (int*)alloc(NE);
  int* dsort = (int*)alloc(NE);
  unsigned short* Wswz = (unsigned short*)alloc((NC * WSZ_L + 1) / 2);
  unsigned short* Wn = (unsigned short*)alloc((NC * 2 * WNP_L + 1) / 2);
  bf16x8* eaf = (bf16x8*)alloc((size_t)NTILES * 768 * 4);
  ushort4* msgc = (ushort4*)alloc((size_t)NE * C2 / 2);

  const int* srcp = ei;
  const int* dstp = ei + NE;

  // CSR build
  hipMemsetAsync(deg, 0, NN * sizeof(int), stream);
  k_hist<<<2048, 256, 0, stream>>>(srcp, deg);
  k_scan<<<1, 1024, 0, stream>>>(deg, cursor);
  k_scatter<<<2048, 256, 0, stream>>>(srcp, dstp, cursor, eid, ssort, dsort);

  k_wprep<<<(NC * WSZ_L + 255) / 256, 256, 0, stream>>>(convW, Wswz);
  k_wprep2<<<(NC * 2 * WNP_L + 255) / 256, 256, 0, stream>>>(convW, Wn);
  k_eaprep<<<(NTILES * 768 + 255) / 256, 256, 0, stream>>>(eid, ea, eaf);
  k_embed<<<NN / 2, 256, 0, stream>>>(x, embW, embb, h0, hbf);

  float* hc = h0;
  float* hn = h1;
  for (int L = 0; L < NC; ++L) {
    const unsigned short* Wl = Wswz + (size_t)L * WSZ_L;
    const float* bL = convb + (size_t)L * C2;
    hipMemsetAsync(st_i, 0, 2 * C2 * sizeof(float), stream);
    hipMemsetAsync(st_o, 0, 2 * HD * sizeof(float), stream);
    hipMemsetAsync(agg, 0, (size_t)NN * HD * sizeof(float), stream);

    dim3 npgrid((NN + 63) / 64, 2);
    k_nodeproj2<<<npgrid, 256, 0, stream>>>(hbf, Wn, L, P1b, P3b);
    k_estat2<<<2500, 256, 0, stream>>>(ssort, dsort, eaf, Wl, bL, P1b, P3b, msgc, st_i);
    k_bnfin<<<1, 256, 0, stream>>>(st_i, 1.f / NE, big + L * C2, bib + L * C2, C2, bnsi);
    k_apply2<<<2500, 256, 0, stream>>>(ssort, msgc, bnsi, agg);
    k_aggstat<<<512, 256, 0, stream>>>(agg, st_o);
    k_bnfin<<<1, 256, 0, stream>>>(st_o, 1.f / NN, bog + L * HD, bob + L * HD, HD, bnso);
    k_update<<<2048, 256, 0, stream>>>(hc, agg, bnso, hn, hbf);
    float* tmp = hc; hc = hn; hn = tmp;
  }

  hipMemsetAsync(psum, 0, (size_t)NG * HD * sizeof(float), stream);
  hipMemsetAsync(pcnt, 0, NG * sizeof(int), stream);
  k_pool<<<2048, 256, 0, stream>>>(hc, batch, psum, pcnt);
  k_head<<<NG, 128, 0, stream>>>(psum, pcnt, linW, linb, outW, outb, out);
}

// Round 6
// 2291.355 us; speedup vs baseline: 3.0167x; 1.1646x over previous
//
#include <hip/hip_runtime.h>

constexpr int NN = 50000;
constexpr int NE = 800000;
constexpr int XD = 92;
constexpr int ED = 80;
constexpr int HD = 128;
constexpr int C2 = 256;   // 2*HD
constexpr int IND = 336;  // 2*HD + ED
constexpr int NC = 3;
constexpr int NG = 256;
constexpr int NTILES = NE / 64;      // 12500
constexpr int WSZ_L = 16 * 3 * 64 * 8;   // per-layer swizzled W2 frags (ushort)
constexpr int WNP_L = 16 * 4 * 64 * 8;   // per-(layer,half) nodeproj W frags

#define DINL __device__ __forceinline__

typedef __attribute__((ext_vector_type(8))) short bf16x8;
typedef __attribute__((ext_vector_type(4))) float f32x4;

DINL short f2bf(float f) {
  unsigned u = __float_as_uint(f);
  u = (u + 0x7fffu + ((u >> 16) & 1u)) >> 16;
  return (short)u;
}
DINL float bf2f(unsigned short u) { return __uint_as_float(((unsigned)u) << 16); }
DINL float rcp_(float x) {
  float r;
  asm("v_rcp_f32 %0, %1" : "=v"(r) : "v"(x));
  return r;
}
DINL float softplusf_(float x) { return x > 20.f ? x : log1pf(__expf(x)); }
// fast gate: sigmoid(f) * softplus(c)
DINL float gate_(float f, float cr) {
  float e = __expf(-f);
  float s = rcp_(1.f + e);
  float t = __expf(cr);
  float l = (cr > 15.f) ? cr : __logf(1.f + t);
  return s * l;
}

template <int CTRL>
DINL int dpp_i(int old_, int src) {
  return __builtin_amdgcn_update_dpp(old_, src, CTRL, 0xF, 0xF, false);
}
template <int CTRL>
DINL float dpp_f(float old_, float src) {
  return __int_as_float(
      __builtin_amdgcn_update_dpp(__float_as_int(old_), __float_as_int(src), CTRL, 0xF, 0xF, false));
}
constexpr int SHR1 = 0x111, SHR2 = 0x112, SHR4 = 0x114, SHR8 = 0x118, SHL1 = 0x101;

// ---------------- embed ----------------
__global__ __launch_bounds__(256) void k_embed(const float* __restrict__ x,
    const float* __restrict__ W, const float* __restrict__ b, float* __restrict__ h,
    unsigned short* __restrict__ hbf) {
  __shared__ float xs[2][XD];
  int t = threadIdx.x;
  int n0 = blockIdx.x * 2;
  for (int i = t; i < 2 * XD; i += 256) xs[i / XD][i % XD] = x[(size_t)n0 * XD + i];
  __syncthreads();
  int lo = t >> 7, c = t & 127;
  float acc = b[c];
  for (int k = 0; k < XD; ++k) acc = fmaf(xs[lo][k], W[k * HD + c], acc);
  h[(size_t)(n0 + lo) * HD + c] = acc;
  hbf[(size_t)(n0 + lo) * HD + c] = (unsigned short)f2bf(acc);
}

// ---------------- CSR build ----------------
__global__ __launch_bounds__(256) void k_hist(const int* __restrict__ src,
                                              int* __restrict__ deg) {
  for (int e = blockIdx.x * 256 + threadIdx.x; e < NE; e += gridDim.x * 256)
    atomicAdd(&deg[src[e]], 1);
}

__global__ __launch_bounds__(1024) void k_scan(const int* __restrict__ deg,
                                               int* __restrict__ cursor) {
  __shared__ int sums[1024];
  int t = threadIdx.x;
  const int CH = 49;
  int b0 = t * CH;
  int s = 0;
  for (int i = 0; i < CH; ++i) {
    int idx = b0 + i;
    if (idx < NN) s += deg[idx];
  }
  sums[t] = s;
  __syncthreads();
  for (int off = 1; off < 1024; off <<= 1) {
    int v = (t >= off) ? sums[t - off] : 0;
    __syncthreads();
    sums[t] += v;
    __syncthreads();
  }
  int excl = (t == 0) ? 0 : sums[t - 1];
  for (int i = 0; i < CH; ++i) {
    int idx = b0 + i;
    if (idx < NN) {
      cursor[idx] = excl;
      excl += deg[idx];
    }
  }
}

__global__ __launch_bounds__(256) void k_scatter(const int* __restrict__ src,
    const int* __restrict__ dst, int* __restrict__ cursor, int* __restrict__ eid,
    int* __restrict__ ssort, int* __restrict__ dsort) {
  for (int e = blockIdx.x * 256 + threadIdx.x; e < NE; e += gridDim.x * 256) {
    int s = src[e];
    int pos = atomicAdd(&cursor[s], 1);
    eid[pos] = e;
    ssort[pos] = s;
    dsort[pos] = dst[e];
  }
}

// ---------------- W2 -> edge-GEMM MFMA fragments ----------------
__global__ __launch_bounds__(256) void k_wprep(const float* __restrict__ convW,
                                               unsigned short* __restrict__ Wswz) {
  int idx = blockIdx.x * 256 + threadIdx.x;
  if (idx >= NC * WSZ_L) return;
  int L = idx / WSZ_L;
  int rem = idx - L * WSZ_L;
  int mt = rem / 1536;
  int rem2 = rem - mt * 1536;
  int ks = rem2 >> 9;
  int lane = (rem2 >> 3) & 63;
  int j = rem2 & 7;
  int k = ks * 32 + (lane >> 4) * 8 + j;
  int m = mt * 16 + (lane & 15);
  float v = (k < ED) ? convW[(size_t)L * IND * C2 + (size_t)(HD + k) * C2 + m] : 0.f;
  Wswz[idx] = (unsigned short)f2bf(v);
}

// ---------------- W1/W3 -> nodeproj MFMA fragments ----------------
__global__ __launch_bounds__(256) void k_wprep2(const float* __restrict__ convW,
                                                unsigned short* __restrict__ Wn) {
  int idx = blockIdx.x * 256 + threadIdx.x;
  if (idx >= NC * 2 * WNP_L) return;
  int Lh = idx >> 15;
  int L = Lh >> 1, half = Lh & 1;
  int rem = idx & 32767;
  int mt = rem >> 11;
  int rem2 = rem & 2047;
  int ks = rem2 >> 9;
  int lane = (rem2 >> 3) & 63;
  int j = rem2 & 7;
  int k = ks * 32 + (lane >> 4) * 8 + j;
  int m = mt * 16 + (lane & 15);
  int row = (half ? 208 : 0) + k;
  Wn[idx] = (unsigned short)f2bf(convW[(size_t)L * IND * C2 + (size_t)row * C2 + m]);
}

// ---------------- nodeproj via MFMA ----------------
__global__ __launch_bounds__(256) void k_nodeproj2(const unsigned short* __restrict__ hbf,
    const unsigned short* __restrict__ Wn, int L,
    ushort4* __restrict__ P1, ushort4* __restrict__ P3) {
  __shared__ bf16x8 hls[1024];
  __shared__ ushort4 outls[4096];
  int t = threadIdx.x, w = t >> 6, l = t & 63, g = l >> 4, c = l & 15;
  int n0 = blockIdx.x * 64;
  int half = blockIdx.y;
  for (int i = t; i < 1024; i += 256) {
    int node = i >> 4, chunk = i & 15;
    int gn = n0 + node;
    if (gn >= NN) gn = NN - 1;
    bf16x8 v = *(const bf16x8*)(hbf + (size_t)gn * HD + chunk * 8);
    hls[node * 16 + (chunk ^ (node & 7))] = v;
  }
  __syncthreads();
  const bf16x8* Wf = (const bf16x8*)(Wn + ((size_t)(L * 2 + half)) * WNP_L);
  bf16x8 af[4][4];
#pragma unroll
  for (int mm = 0; mm < 4; ++mm)
#pragma unroll
    for (int ks = 0; ks < 4; ++ks) af[mm][ks] = Wf[((w * 4 + mm) * 4 + ks) * 64 + l];
  f32x4 acc[4][4];
#pragma unroll
  for (int mm = 0; mm < 4; ++mm)
#pragma unroll
    for (int nt = 0; nt < 4; ++nt)
#pragma unroll
      for (int i = 0; i < 4; ++i) acc[mm][nt][i] = 0.f;
#pragma unroll
  for (int nt = 0; nt < 4; ++nt) {
    int node = nt * 16 + c;
#pragma unroll
    for (int ks = 0; ks < 4; ++ks) {
      bf16x8 b = hls[node * 16 + ((4 * ks + g) ^ (node & 7))];
#pragma unroll
      for (int mm = 0; mm < 4; ++mm)
        acc[mm][nt] = __builtin_amdgcn_mfma_f32_16x16x32_bf16(af[mm][ks], b, acc[mm][nt], 0, 0, 0);
    }
  }
  __syncthreads();
#pragma unroll
  for (int mm = 0; mm < 4; ++mm)
#pragma unroll
    for (int nt = 0; nt < 4; ++nt) {
      int node = nt * 16 + c;
      int quad = (w * 4 + mm) * 4 + g;
      ushort4 st;
      st.x = (unsigned short)f2bf(acc[mm][nt][0]);
      st.y = (unsigned short)f2bf(acc[mm][nt][1]);
      st.z = (unsigned short)f2bf(acc[mm][nt][2]);
      st.w = (unsigned short)f2bf(acc[mm][nt][3]);
      outls[node * 64 + (quad ^ ((node & 7) << 3))] = st;
    }
  __syncthreads();
  ushort4* P = half ? P3 : P1;
  for (int i = t; i < 4096; i += 256) {
    int row = i >> 6, quad = i & 63;
    int gn = n0 + row;
    if (gn < NN) P[(size_t)gn * 64 + quad] = outls[row * 64 + (quad ^ ((row & 7) << 3))];
  }
}

// ---------------- ea -> CSR-ordered MFMA B-fragments ----------------
__global__ __launch_bounds__(256) void k_eaprep(const int* __restrict__ eid,
    const float* __restrict__ ea, bf16x8* __restrict__ eaf) {
  int idx = blockIdx.x * 256 + threadIdx.x;
  if (idx >= NTILES * 768) return;
  int tile = idx / 768;
  int r = idx - tile * 768;
  int fr = r >> 6, l = r & 63;
  int nt = fr / 3, ks = fr - 3 * nt;
  int c = l & 15, g = l >> 4;
  int k0 = ks * 32 + g * 8;
  bf16x8 v;
  if (k0 < ED) {
    int e = eid[tile * 64 + nt * 16 + c];
    const float* p = ea + (size_t)e * ED + k0;
    float4 x0 = *(const float4*)p;
    float4 x1 = *(const float4*)(p + 4);
    v[0] = f2bf(x0.x); v[1] = f2bf(x0.y); v[2] = f2bf(x0.z); v[3] = f2bf(x0.w);
    v[4] = f2bf(x1.x); v[5] = f2bf(x1.y); v[6] = f2bf(x1.z); v[7] = f2bf(x1.w);
  } else {
#pragma unroll
    for (int j = 0; j < 8; ++j) v[j] = 0;
  }
  eaf[idx] = v;
}

// ---------------- pass 1 (pipelined): MFMA + gathers + stats + msg store ----------------
// s/d indices rotated one tile ahead; all loads issued in one burst before MFMAs.
// NOTE: conv bias omitted — BN is shift-invariant, so it cancels exactly.
__global__ __launch_bounds__(256, 2) void k_estat2(
    const int* __restrict__ ssort, const int* __restrict__ dsort,
    const bf16x8* __restrict__ eaf, const unsigned short* __restrict__ Wswz,
    const ushort4* __restrict__ P1b, const ushort4* __restrict__ P3b,
    ushort4* __restrict__ msgc, float* __restrict__ stats) {
  int t = threadIdx.x;
  int w = t >> 6, l = t & 63;
  int g = l >> 4, c = l & 15;
  int mtg[4] = {2 * w, 2 * w + 1, 2 * w + 8, 2 * w + 9};
  const bf16x8* Wf = (const bf16x8*)Wswz;
  bf16x8 af[4][3];
#pragma unroll
  for (int m = 0; m < 4; ++m)
#pragma unroll
    for (int ks = 0; ks < 3; ++ks) af[m][ks] = Wf[(mtg[m] * 3 + ks) * 64 + l];
  f32x4 ssum[4], ssq[4];
#pragma unroll
  for (int m = 0; m < 4; ++m)
#pragma unroll
    for (int i = 0; i < 4; ++i) { ssum[m][i] = 0.f; ssq[m][i] = 0.f; }

  const int stride = gridDim.x;
  int tile = blockIdx.x;
  int s_[4], d_[4];
  if (tile < NTILES) {
#pragma unroll
    for (int nt = 0; nt < 4; ++nt) {
      s_[nt] = ssort[tile * 64 + nt * 16 + c];
      d_[nt] = dsort[tile * 64 + nt * 16 + c];
    }
  }
  for (; tile < NTILES; tile += stride) {
    // burst 1: eaf fragments for this tile (linear)
    bf16x8 b_[12];
    const bf16x8* bp = eaf + (size_t)tile * 768 + l;
#pragma unroll
    for (int fr = 0; fr < 12; ++fr) b_[fr] = bp[fr * 64];
    // burst 2: all P gathers for this tile (addresses ready from rotation)
    ushort4 q1[4][4], q3[4][4];
#pragma unroll
    for (int nt = 0; nt < 4; ++nt)
#pragma unroll
      for (int m = 0; m < 4; ++m) {
        q1[nt][m] = P1b[(size_t)s_[nt] * 64 + mtg[m] * 4 + g];
        q3[nt][m] = P3b[(size_t)d_[nt] * 64 + mtg[m] * 4 + g];
      }
    // burst 3: next tile's indices
    int sn[4], dn[4];
    int tn = tile + stride;
    if (tn < NTILES) {
#pragma unroll
      for (int nt = 0; nt < 4; ++nt) {
        sn[nt] = ssort[tn * 64 + nt * 16 + c];
        dn[nt] = dsort[tn * 64 + nt * 16 + c];
      }
    } else {
#pragma unroll
      for (int nt = 0; nt < 4; ++nt) { sn[nt] = 0; dn[nt] = 0; }
    }
    // compute: MFMAs cover gather latency
#pragma unroll
    for (int nt = 0; nt < 4; ++nt) {
      f32x4 acc[4];
#pragma unroll
      for (int m = 0; m < 4; ++m) {
        acc[m][0] = 0.f; acc[m][1] = 0.f; acc[m][2] = 0.f; acc[m][3] = 0.f;
      }
#pragma unroll
      for (int ks = 0; ks < 3; ++ks)
#pragma unroll
        for (int m = 0; m < 4; ++m)
          acc[m] = __builtin_amdgcn_mfma_f32_16x16x32_bf16(af[m][ks], b_[nt * 3 + ks],
                                                           acc[m], 0, 0, 0);
#pragma unroll
      for (int m = 0; m < 4; ++m) {
        f32x4 ms;
        ms[0] = acc[m][0] + bf2f(q1[nt][m].x) + bf2f(q3[nt][m].x);
        ms[1] = acc[m][1] + bf2f(q1[nt][m].y) + bf2f(q3[nt][m].y);
        ms[2] = acc[m][2] + bf2f(q1[nt][m].z) + bf2f(q3[nt][m].z);
        ms[3] = acc[m][3] + bf2f(q1[nt][m].w) + bf2f(q3[nt][m].w);
#pragma unroll
        for (int i = 0; i < 4; ++i) {
          ssum[m][i] += ms[i];
          ssq[m][i] = fmaf(ms[i], ms[i], ssq[m][i]);
        }
        ushort4 st;
        st.x = (unsigned short)f2bf(ms[0]);
        st.y = (unsigned short)f2bf(ms[1]);
        st.z = (unsigned short)f2bf(ms[2]);
        st.w = (unsigned short)f2bf(ms[3]);
        msgc[(((size_t)tile * 4 + nt) * 16 + w * 4 + m) * 64 + l] = st;
      }
    }
#pragma unroll
    for (int nt = 0; nt < 4; ++nt) { s_[nt] = sn[nt]; d_[nt] = dn[nt]; }
  }
#pragma unroll
  for (int off = 1; off < 16; off <<= 1)
#pragma unroll
    for (int m = 0; m < 4; ++m)
#pragma unroll
      for (int i = 0; i < 4; ++i) {
        ssum[m][i] += __shfl_xor(ssum[m][i], off, 16);
        ssq[m][i] += __shfl_xor(ssq[m][i], off, 16);
      }
  if (c == 0) {
#pragma unroll
    for (int m = 0; m < 4; ++m)
#pragma unroll
      for (int i = 0; i < 4; ++i) {
        int ch = mtg[m] * 16 + 4 * g + i;
        atomicAdd(&stats[ch], ssum[m][i]);
        atomicAdd(&stats[C2 + ch], ssq[m][i]);
      }
  }
}

// ---------------- pass 2: BN(from stats, inline) + gate + DPP segmented scatter ----------------
__global__ __launch_bounds__(256) void k_apply2(
    const int* __restrict__ ssort, const ushort4* __restrict__ msgc,
    const float* __restrict__ st, const float* __restrict__ gammaI,
    const float* __restrict__ betaI, float* __restrict__ agg) {
  int t = threadIdx.x;
  int w = t >> 6, l = t & 63;
  int g = l >> 4, c = l & 15;
  int mtg[4] = {2 * w, 2 * w + 1, 2 * w + 8, 2 * w + 9};
  f32x4 sc4[4], sh4[4];
#pragma unroll
  for (int m = 0; m < 4; ++m)
#pragma unroll
    for (int i = 0; i < 4; ++i) {
      int ch = mtg[m] * 16 + 4 * g + i;
      float mean = st[ch] * (1.f / NE);
      float var = st[C2 + ch] * (1.f / NE) - mean * mean;
      float scv = gammaI[ch] * rsqrtf(var + 1e-5f);
      sc4[m][i] = scv;
      sh4[m][i] = betaI[ch] - mean * scv;
    }
  for (int tile = blockIdx.x; tile < NTILES; tile += gridDim.x) {
    int e0 = tile * 64;
    int s_[4];
#pragma unroll
    for (int nt = 0; nt < 4; ++nt) s_[nt] = ssort[e0 + nt * 16 + c];
    ushort4 mw[4][4];
#pragma unroll
    for (int nt = 0; nt < 4; ++nt)
#pragma unroll
      for (int m = 0; m < 4; ++m)
        mw[nt][m] = msgc[(((size_t)tile * 4 + nt) * 16 + w * 4 + m) * 64 + l];
#pragma unroll
    for (int nt = 0; nt < 4; ++nt) {
      int sv = s_[nt];
      int ps = dpp_i<SHR1>(-1, sv);
      int hp = (ps != sv) ? c : 0;
      hp = max(hp, dpp_i<SHR1>(0, hp));
      hp = max(hp, dpp_i<SHR2>(0, hp));
      hp = max(hp, dpp_i<SHR4>(0, hp));
      hp = max(hp, dpp_i<SHR8>(0, hp));
      int ns = dpp_i<SHL1>(-1, sv);
      bool tail = (ns != sv);
      bool g1 = (c - 1) >= hp, g2 = (c - 2) >= hp, g4 = (c - 4) >= hp, g8 = (c - 8) >= hp;
      f32x4 v4[4];
#pragma unroll
      for (int m = 0; m < 4; ++m) {
        v4[m][0] = fmaf(bf2f(mw[nt][m].x), sc4[m][0], sh4[m][0]);
        v4[m][1] = fmaf(bf2f(mw[nt][m].y), sc4[m][1], sh4[m][1]);
        v4[m][2] = fmaf(bf2f(mw[nt][m].z), sc4[m][2], sh4[m][2]);
        v4[m][3] = fmaf(bf2f(mw[nt][m].w), sc4[m][3], sh4[m][3]);
      }
      float gg_[8];
#pragma unroll
      for (int p = 0; p < 2; ++p)
#pragma unroll
        for (int i = 0; i < 4; ++i)
          gg_[p * 4 + i] = gate_(v4[p][i], v4[p + 2][i]);
#pragma unroll
      for (int q = 0; q < 8; ++q) {
        float tv;
        tv = dpp_f<SHR1>(0.f, gg_[q]); gg_[q] += g1 ? tv : 0.f;
        tv = dpp_f<SHR2>(0.f, gg_[q]); gg_[q] += g2 ? tv : 0.f;
        tv = dpp_f<SHR4>(0.f, gg_[q]); gg_[q] += g4 ? tv : 0.f;
        tv = dpp_f<SHR8>(0.f, gg_[q]); gg_[q] += g8 ? tv : 0.f;
      }
      if (tail) {
#pragma unroll
        for (int p = 0; p < 2; ++p)
#pragma unroll
          for (int i = 0; i < 4; ++i)
            atomicAdd(&agg[(size_t)sv * HD + mtg[p] * 16 + 4 * g + i], gg_[p * 4 + i]);
      }
    }
  }
}

// ---------------- agg BN stats ----------------
__global__ __launch_bounds__(256) void k_aggstat(const float* __restrict__ agg,
                                                 float* __restrict__ stats) {
  int t = threadIdx.x;
  int c = t & 127, half = t >> 7;
  float s = 0.f, sq = 0.f;
  for (int n = blockIdx.x * 2 + half; n < NN; n += gridDim.x * 2) {
    float v = agg[(size_t)n * HD + c];
    s += v;
    sq = fmaf(v, v, sq);
  }
  __shared__ float shs[2][128], shq[2][128];
  shs[half][c] = s;
  shq[half][c] = sq;
  __syncthreads();
  if (t < 128) {
    atomicAdd(&stats[c], shs[0][c] + shs[1][c]);
    atomicAdd(&stats[128 + c], shq[0][c] + shq[1][c]);
  }
}

// ---------------- h update (BN inline from st_o) ----------------
__global__ __launch_bounds__(256) void k_update(const float* __restrict__ h,
    const float* __restrict__ agg, const float* __restrict__ st_o,
    const float* __restrict__ bog, const float* __restrict__ bob,
    float* __restrict__ hn, unsigned short* __restrict__ hbf) {
  int stride = gridDim.x * 256;
  for (int i = blockIdx.x * 256 + threadIdx.x; i < NN * HD; i += stride) {
    int c = i & 127;
    float mean = st_o[c] * (1.f / NN);
    float var = st_o[128 + c] * (1.f / NN) - mean * mean;
    float scv = bog[c] * rsqrtf(var + 1e-5f);
    float shv = bob[c] - mean * scv;
    float v = h[i] + fmaf(agg[i], scv, shv);
    float r = softplusf_(v);
    hn[i] = r;
    hbf[i] = (unsigned short)f2bf(r);
  }
}

// ---------------- pooling ----------------
__global__ __launch_bounds__(256) void k_pool(const float* __restrict__ h,
    const int* __restrict__ batch, float* __restrict__ psum, int* __restrict__ pcnt) {
  int stride = gridDim.x * 256;
  for (int i = blockIdx.x * 256 + threadIdx.x; i < NN * HD; i += stride) {
    int n = i >> 7, c = i & 127;
    int g = batch[n];
    atomicAdd(&psum[g * HD + c], h[i]);
    if (c == 0) atomicAdd(&pcnt[g], 1);
  }
}

// ---------------- head ----------------
__global__ __launch_bounds__(128) void k_head(const float* __restrict__ psum,
    const int* __restrict__ pcnt, const float* __restrict__ linW,
    const float* __restrict__ linb, const float* __restrict__ outW,
    const float* __restrict__ outb, float* __restrict__ out) {
  __shared__ float pl[HD];
  __shared__ float red[2];
  int g = blockIdx.x, t = threadIdx.x;
  float cnt = fmaxf((float)pcnt[g], 1.f);
  pl[t] = psum[g * HD + t] / cnt;
  __syncthreads();
  float acc = linb[t];
  for (int k = 0; k < HD; ++k) acc = fmaf(pl[k], linW[k * HD + t], acc);
  float term = softplusf_(acc) * outW[t];
#pragma unroll
  for (int off = 32; off > 0; off >>= 1) term += __shfl_down(term, off, 64);
  if ((t & 63) == 0) red[t >> 6] = term;
  __syncthreads();
  if (t == 0) out[g] = red[0] + red[1] + outb[0];
}

extern "C" void kernel_launch(void* const* d_in, const int* in_sizes, int n_in,
                              void* d_out, int out_size, void* d_ws, size_t ws_size,
                              hipStream_t stream) {
  const float* x = (const float*)d_in[0];
  const int* ei = (const int*)d_in[1];
  const float* ea = (const float*)d_in[2];
  const int* batch = (const int*)d_in[3];
  const float* embW = (const float*)d_in[4];
  const float* embb = (const float*)d_in[5];
  const float* convW = (const float*)d_in[6];
  // convb (d_in[7]) cancels inside BN — unused.
  const float* big = (const float*)d_in[8];
  const float* bib = (const float*)d_in[9];
  const float* bog = (const float*)d_in[10];
  const float* bob = (const float*)d_in[11];
  const float* linW = (const float*)d_in[12];
  const float* linb = (const float*)d_in[13];
  const float* outW = (const float*)d_in[14];
  const float* outb = (const float*)d_in[15];
  float* out = (float*)d_out;

  float* wsf = (float*)d_ws;
  size_t off = 0;
  auto alloc = [&](size_t n) {
    float* p = wsf + off;
    off += (n + 3) & ~(size_t)3;
    return p;
  };
  float* h0 = alloc((size_t)NN * HD);
  float* h1 = alloc((size_t)NN * HD);
  unsigned short* hbf = (unsigned short*)alloc((size_t)NN * HD / 2);
  ushort4* P1b = (ushort4*)alloc((size_t)NN * C2 / 2);
  ushort4* P3b = (ushort4*)alloc((size_t)NN * C2 / 2);
  float* agg = alloc((size_t)NN * HD);
  float* st_i = alloc(2 * C2);
  float* st_o = alloc(2 * HD);
  float* psum = alloc((size_t)NG * HD);
  int* pcnt = (int*)alloc(NG);
  int* deg = (int*)alloc(NN);
  int* cursor = (int*)alloc(NN);
  int* eid = (int*)alloc(NE);
  int* ssort = (int*)alloc(NE);
  int* dsort = (int*)alloc(NE);
  unsigned short* Wswz = (unsigned short*)alloc((NC * WSZ_L + 1) / 2);
  unsigned short* Wn = (unsigned short*)alloc((NC * 2 * WNP_L + 1) / 2);
  bf16x8* eaf = (bf16x8*)alloc((size_t)NTILES * 768 * 4);
  ushort4* msgc = (ushort4*)alloc((size_t)NE * C2 / 2);

  const int* srcp = ei;
  const int* dstp = ei + NE;

  hipMemsetAsync(deg, 0, NN * sizeof(int), stream);
  k_hist<<<2048, 256, 0, stream>>>(srcp, deg);
  k_scan<<<1, 1024, 0, stream>>>(deg, cursor);
  k_scatter<<<2048, 256, 0, stream>>>(srcp, dstp, cursor, eid, ssort, dsort);

  k_wprep<<<(NC * WSZ_L + 255) / 256, 256, 0, stream>>>(convW, Wswz);
  k_wprep2<<<(NC * 2 * WNP_L + 255) / 256, 256, 0, stream>>>(convW, Wn);
  k_eaprep<<<(NTILES * 768 + 255) / 256, 256, 0, stream>>>(eid, ea, eaf);
  k_embed<<<NN / 2, 256, 0, stream>>>(x, embW, embb, h0, hbf);

  float* hc = h0;
  float* hn = h1;
  for (int L = 0; L < NC; ++L) {
    const unsigned short* Wl = Wswz + (size_t)L * WSZ_L;
    hipMemsetAsync(st_i, 0, 2 * C2 * sizeof(float), stream);
    hipMemsetAsync(st_o, 0, 2 * HD * sizeof(float), stream);
    hipMemsetAsync(agg, 0, (size_t)NN * HD * sizeof(float), stream);

    dim3 npgrid((NN + 63) / 64, 2);
    k_nodeproj2<<<npgrid, 256, 0, stream>>>(hbf, Wn, L, P1b, P3b);
    k_estat2<<<2500, 256, 0, stream>>>(ssort, dsort, eaf, Wl, P1b, P3b, msgc, st_i);
    k_apply2<<<2500, 256, 0, stream>>>(ssort, msgc, st_i, big + L * C2, bib + L * C2, agg);
    k_aggstat<<<512, 256, 0, stream>>>(agg, st_o);
    k_update<<<2048, 256, 0, stream>>>(hc, agg, st_o, bog + L * HD, bob + L * HD, hn, hbf);
    float* tmp = hc; hc = hn; hn = tmp;
  }

  hipMemsetAsync(psum, 0, (size_t)NG * HD * sizeof(float), stream);
  hipMemsetAsync(pcnt, 0, NG * sizeof(int), stream);
  k_pool<<<2048, 256, 0, stream>>>(hc, batch, psum, pcnt);
  k_head<<<NG, 128, 0, stream>>>(psum, pcnt, linW, linb, outW, outb, out);
}